// Round 8
// baseline (492.465 us; speedup 1.0000x reference)
//
#include <hip/hip_runtime.h>
#include <math.h>

#define N_NODES 2000
#define NA 16
#define NOBS 64
#define NH 128
#define NE 16000
#define NITERS 8

// ---------------- workspace layout (float offsets) ----------------
#define WS_MSG0      0                       // 512000
#define WS_Q         512000                  // 8
#define WS_DEG       512008                  // int[2000]
#define WS_CUR       514008                  // int[2000]
#define WS_ZERO_CNT  516008                  // msg0+q+deg+cur zeroed in setup
#define WS_MSG1      516008                  // 512000
#define WS_AIDX      1028008                 // int[8*2000]
#define WS_BASE      1044008                 // int[2001]
#define WS_CSR       1046012                 // int[32000]
#define WS_W         1078012                 // int[16000] wflag
#define WS_PT        1094016                 // pT 4,096,000; owner map (4,000,000 ints) aliases
#define WS_GIT       (WS_PT + 4000000)       // gru wihT k-panel 80x384 = 30720 (dead after gru)
#define WS_GHT       (WS_GIT + 30720)        // gru whhT k-panel 128x384 = 49152
#define WS_WB        5190016                 // transposed weights base
#define WS_UW0T      (WS_WB + 0)             // 128x256
#define WS_UW1T      (WS_WB + 32768)         // 256x256
#define WS_UW2T      (WS_WB + 98304)         // 256x16
#define WS_PW0T      (WS_WB + 102400)        // 256x128
#define WS_PW1T      (WS_WB + 135168)        // 128x256
#define WS_PW2T      (WS_WB + 167936)        // 256x256
#define WS_PW3T      (WS_WB + 233472)        // 256x16
#define WS_PW4T      (WS_WB + 237568)        // 16x256
// end: 5,431,680 floats (~21.7 MB)
// NOTE: weight ping-pong prefetch reads up to ~2K floats past an array's
// end — always lands in the NEXT array (never used on the last array, PW4T).

// ---------------- setup: zero msg0/q/deg/cur, transpose weights -------------
__global__ __launch_bounds__(256) void setup_kernel(
    float* __restrict__ ws,
    const float* __restrict__ uW0, const float* __restrict__ uW1,
    const float* __restrict__ uW2, const float* __restrict__ pW0,
    const float* __restrict__ pW1, const float* __restrict__ pW2,
    const float* __restrict__ pW3, const float* __restrict__ pW4,
    const float* __restrict__ gwih, const float* __restrict__ gwhh)
{
    const int total = WS_ZERO_CNT + 321536;
    for (int idx = blockIdx.x * 256 + threadIdx.x; idx < total;
         idx += gridDim.x * 256) {
        if (idx < WS_ZERO_CNT) {
            ws[idx] = 0.f;
        } else {
            int t = idx - WS_ZERO_CNT;
            if (t < 241664) {
                const float* src; float* dst; int K, O;
                if      (t < 32768)              { src = uW0;  dst = ws + WS_UW0T; K = 128; O = 256; }
                else if (t < 98304)  { t -= 32768;  src = uW1;  dst = ws + WS_UW1T; K = 256; O = 256; }
                else if (t < 102400) { t -= 98304;  src = uW2;  dst = ws + WS_UW2T; K = 256; O = 16;  }
                else if (t < 135168) { t -= 102400; src = pW0;  dst = ws + WS_PW0T; K = 256; O = 128; }
                else if (t < 167936) { t -= 135168; src = pW1;  dst = ws + WS_PW1T; K = 128; O = 256; }
                else if (t < 233472) { t -= 167936; src = pW2;  dst = ws + WS_PW2T; K = 256; O = 256; }
                else if (t < 237568) { t -= 233472; src = pW3;  dst = ws + WS_PW3T; K = 256; O = 16;  }
                else                 { t -= 237568; src = pW4;  dst = ws + WS_PW4T; K = 16;  O = 256; }
                int k = t / O, o = t % O;
                dst[t] = src[o * K + k];
                (void)K;
            } else if (t < 272384) {
                t -= 241664;   // gru wihT k-panel: dst[k4*1536+g*4+c] = gwih[g*80+4k4+c]
                int k4 = t / 1536, r = t % 1536, g = r >> 2, c = r & 3;
                ws[WS_GIT + t] = gwih[g * 80 + 4 * k4 + c];
            } else {
                t -= 272384;
                int k4 = t / 1536, r = t % 1536, g = r >> 2, c = r & 3;
                ws[WS_GHT + t] = gwhh[g * 128 + 4 * k4 + c];
            }
        }
    }
}

// ---------------- dedup + CSR build ------------------------------------------
__global__ __launch_bounds__(256) void init_owner_kernel(
    const int* __restrict__ edges, int* __restrict__ owner)
{
    int e = blockIdx.x * 256 + threadIdx.x;
    if (e < NE) {
        int i = edges[2 * e], j = edges[2 * e + 1];
        owner[i * N_NODES + j] = -1;
    }
}

__global__ __launch_bounds__(256) void claim_kernel(
    const int* __restrict__ edges, int* __restrict__ owner)
{
    int e = blockIdx.x * 256 + threadIdx.x;
    if (e < NE) {
        int i = edges[2 * e], j = edges[2 * e + 1];
        atomicMax(&owner[i * N_NODES + j], e);
    }
}

__global__ __launch_bounds__(256) void resolve_kernel(
    const int* __restrict__ edges, const int* __restrict__ owner,
    int* __restrict__ wflag, int* __restrict__ deg)
{
    int e = blockIdx.x * 256 + threadIdx.x;
    if (e < NE) {
        int i = edges[2 * e], j = edges[2 * e + 1];
        int rep = (owner[i * N_NODES + j] == e) ? 1 : 0;
        wflag[e] = rep;
        if (rep) {
            atomicAdd(&deg[i], 1);
            atomicAdd(&deg[j], 1);
        }
    }
}

// single-block exclusive scan of deg -> base[0..2000]
__global__ __launch_bounds__(256) void scan_kernel(
    const int* __restrict__ deg, int* __restrict__ base)
{
    __shared__ int part[256];
    const int tid = threadIdx.x;
    int mysum = 0;
    #pragma unroll
    for (int k = 0; k < 8; ++k) {
        int n = tid * 8 + k;
        mysum += (n < N_NODES) ? deg[n] : 0;
    }
    part[tid] = mysum;
    __syncthreads();
    for (int off = 1; off < 256; off <<= 1) {
        int v = 0;
        if (tid >= off) v = part[tid - off];
        __syncthreads();
        part[tid] += v;
        __syncthreads();
    }
    int off0 = part[tid] - mysum;
    #pragma unroll
    for (int k = 0; k < 8; ++k) {
        int n = tid * 8 + k;
        if (n <= N_NODES) base[n] = off0;
        if (n < N_NODES) off0 += deg[n];
    }
}

// fill CSR: representative edges record their two directed msg slots.
// slot e = msg into j; slot NE+e = msg into i.
__global__ __launch_bounds__(256) void fill_kernel(
    const int* __restrict__ edges, const int* __restrict__ wflag,
    const int* __restrict__ base, int* __restrict__ cur,
    int* __restrict__ csr)
{
    int e = blockIdx.x * 256 + threadIdx.x;
    if (e < NE && wflag[e]) {
        int i = edges[2 * e], j = edges[2 * e + 1];
        int pi = atomicAdd(&cur[i], 1);
        csr[base[i] + pi] = NE + e;
        int pj = atomicAdd(&cur[j], 1);
        csr[base[j] + pj] = e;
    }
}

// ---------------- GRU encoder -------------------------------------------------
__global__ __launch_bounds__(256) void gru_kernel(
    const float* __restrict__ x, const float* __restrict__ pa,
    const float* __restrict__ st, const float* __restrict__ wihT,
    const float* __restrict__ whhT, const float* __restrict__ bih,
    const float* __restrict__ bhh, float* __restrict__ h_out)
{
    __shared__ float enc[8][80];
    __shared__ float hp[8][128];
    __shared__ float gi[8][384];
    __shared__ float gh[8][384];
    const int tid = threadIdx.x;
    const int n0 = blockIdx.x * 8;

    for (int idx = tid; idx < 8 * 80; idx += 256) {
        int r = idx / 80, c = idx % 80;
        enc[r][c] = (c < 64) ? x[(n0 + r) * 64 + c] : pa[(n0 + r) * 16 + (c - 64)];
    }
    for (int idx = tid; idx < 8 * 128; idx += 256) {
        int r = idx >> 7, c = idx & 127;
        hp[r][c] = st[(n0 + r) * 128 + c];
    }
    __syncthreads();

    for (int idx = tid; idx < 8 * 384; idx += 256) {
        int g = idx % 384, r = idx / 384;
        float s1 = bih[g];
        #pragma unroll 5
        for (int k4 = 0; k4 < 20; ++k4) {
            const float4 ev = *(const float4*)&enc[r][4 * k4];
            const float4 wv = *(const float4*)&wihT[k4 * 1536 + g * 4];
            s1 = fmaf(ev.x, wv.x, fmaf(ev.y, wv.y, fmaf(ev.z, wv.z, fmaf(ev.w, wv.w, s1))));
        }
        gi[r][g] = s1;
        float s2 = bhh[g];
        #pragma unroll 8
        for (int k4 = 0; k4 < 32; ++k4) {
            const float4 hv = *(const float4*)&hp[r][4 * k4];
            const float4 wv = *(const float4*)&whhT[k4 * 1536 + g * 4];
            s2 = fmaf(hv.x, wv.x, fmaf(hv.y, wv.y, fmaf(hv.z, wv.z, fmaf(hv.w, wv.w, s2))));
        }
        gh[r][g] = s2;
    }
    __syncthreads();

    for (int idx = tid; idx < 8 * 128; idx += 256) {
        int r = idx >> 7, c = idx & 127;
        float rr = 1.f / (1.f + expf(-(gi[r][c] + gh[r][c])));
        float zz = 1.f / (1.f + expf(-(gi[r][128 + c] + gh[r][128 + c])));
        float nn = tanhf(gi[r][256 + c] + rr * gh[r][256 + c]);
        h_out[(n0 + r) * 128 + c] = (1.f - zz) * nn + zz * hp[r][c];
    }
}

// ---------------- u MLP: 128 -> 256 -> 256 -> 16, /N ----------------
__global__ __launch_bounds__(256) void umlp_kernel(
    const float* __restrict__ h, const float* __restrict__ w0t,
    const float* __restrict__ b0, const float* __restrict__ w1t,
    const float* __restrict__ b1, const float* __restrict__ w2t,
    const float* __restrict__ b2, float* __restrict__ u_out)
{
    __shared__ float A[8][128];
    __shared__ float B[8][256];
    const int tid = threadIdx.x;
    const int n0 = blockIdx.x * 8;

    for (int idx = tid; idx < 8 * 128; idx += 256) {
        int r = idx >> 7, c = idx & 127;
        A[r][c] = h[(n0 + r) * 128 + c];
    }
    __syncthreads();
    // L0: 128->256 relu, A->B
    {
        const int o = tid;
        const float* wp = w0t + o;
        float wA[4], wB[4];
        #pragma unroll
        for (int c = 0; c < 4; ++c) wA[c] = wp[c * 256];
        float acc[8];
        #pragma unroll
        for (int r = 0; r < 8; ++r) acc[r] = b0[o];
        for (int k4 = 0; k4 < 32; k4 += 2) {
            #pragma unroll
            for (int c = 0; c < 4; ++c) wB[c] = wp[(4 * (k4 + 1) + c) * 256];
            #pragma unroll
            for (int r = 0; r < 8; ++r) {
                const float4 av = *(const float4*)&A[r][4 * k4];
                acc[r] = fmaf(av.x, wA[0], fmaf(av.y, wA[1], fmaf(av.z, wA[2], fmaf(av.w, wA[3], acc[r]))));
            }
            #pragma unroll
            for (int c = 0; c < 4; ++c) wA[c] = wp[(4 * (k4 + 2) + c) * 256]; // benign OOB at last pair
            #pragma unroll
            for (int r = 0; r < 8; ++r) {
                const float4 av = *(const float4*)&A[r][4 * k4 + 4];
                acc[r] = fmaf(av.x, wB[0], fmaf(av.y, wB[1], fmaf(av.z, wB[2], fmaf(av.w, wB[3], acc[r]))));
            }
        }
        #pragma unroll
        for (int r = 0; r < 8; ++r) B[r][o] = fmaxf(acc[r], 0.f);
    }
    __syncthreads();
    // L1: 256->256 relu, B->B (register staged)
    {
        const int o = tid;
        const float* wp = w1t + o;
        float wA[4], wB[4];
        #pragma unroll
        for (int c = 0; c < 4; ++c) wA[c] = wp[c * 256];
        float acc[8];
        #pragma unroll
        for (int r = 0; r < 8; ++r) acc[r] = b1[o];
        for (int k4 = 0; k4 < 64; k4 += 2) {
            #pragma unroll
            for (int c = 0; c < 4; ++c) wB[c] = wp[(4 * (k4 + 1) + c) * 256];
            #pragma unroll
            for (int r = 0; r < 8; ++r) {
                const float4 av = *(const float4*)&B[r][4 * k4];
                acc[r] = fmaf(av.x, wA[0], fmaf(av.y, wA[1], fmaf(av.z, wA[2], fmaf(av.w, wA[3], acc[r]))));
            }
            #pragma unroll
            for (int c = 0; c < 4; ++c) wA[c] = wp[(4 * (k4 + 2) + c) * 256]; // benign OOB at last pair
            #pragma unroll
            for (int r = 0; r < 8; ++r) {
                const float4 av = *(const float4*)&B[r][4 * k4 + 4];
                acc[r] = fmaf(av.x, wB[0], fmaf(av.y, wB[1], fmaf(av.z, wB[2], fmaf(av.w, wB[3], acc[r]))));
            }
        }
        __syncthreads();
        #pragma unroll
        for (int r = 0; r < 8; ++r) B[r][o] = fmaxf(acc[r], 0.f);
    }
    __syncthreads();
    // L2: 256->16, /N, no relu (threads 0..127)
    if (tid < 128) {
        int r = tid >> 4, o = tid & 15;
        float acc = b2[o];
        for (int k4 = 0; k4 < 64; ++k4) {
            const float4 av = *(const float4*)&B[r][4 * k4];
            acc = fmaf(av.x, w2t[(4 * k4 + 0) * 16 + o],
                  fmaf(av.y, w2t[(4 * k4 + 1) * 16 + o],
                  fmaf(av.z, w2t[(4 * k4 + 2) * 16 + o],
                  fmaf(av.w, w2t[(4 * k4 + 3) * 16 + o], acc))));
        }
        u_out[(n0 + r) * 16 + o] = acc * (1.f / N_NODES);
    }
}

// ---------------- p MLP (round-5 shape: 32 rows, 3 blocks/CU) ----------------
__global__ __launch_bounds__(256, 3) void pmlp_kernel(
    const float* __restrict__ h, const int* __restrict__ edges,
    const float* __restrict__ w0t, const float* __restrict__ b0,
    const float* __restrict__ w1t, const float* __restrict__ b1,
    const float* __restrict__ w2t, const float* __restrict__ b2,
    const float* __restrict__ w3t, const float* __restrict__ b3,
    const float* __restrict__ w4t, const float* __restrict__ b4,
    float* __restrict__ p_out, float* __restrict__ pT)
{
    __shared__ float A[32][256];   // 32 KB
    __shared__ float B[32][128];   // 16 KB
    __shared__ float C16[32][16];  // 2 KB
    __shared__ int fi[32], se[32];
    const int tid = threadIdx.x;
    const int e0 = blockIdx.x * 16;
    const int rg = tid >> 6;       // wave id = row group
    const int ct = tid & 63;
    const int r0 = rg * 8;

    if (tid < 16) {
        int i = edges[2 * (e0 + tid)], j = edges[2 * (e0 + tid) + 1];
        fi[2 * tid] = i;     se[2 * tid] = j;       // row 2s  = [h_i | h_j]
        fi[2 * tid + 1] = j; se[2 * tid + 1] = i;   // row 2s+1 = [h_j | h_i]
    }
    __syncthreads();
    {
        int c = tid, cl = c & 127;
        for (int r = 0; r < 32; ++r) {
            int node = (c < 128) ? fi[r] : se[r];
            A[r][c] = h[node * 128 + cl];
        }
    }
    __syncthreads();
    // L0: 256->128 relu, A->B.  2 cols/thread (float2 weights), ping-pong.
    {
        const float2* wp = (const float2*)w0t + ct;
        float2 wA[4], wB[4];
        #pragma unroll
        for (int c = 0; c < 4; ++c) wA[c] = wp[c * 64];
        float2 bb = ((const float2*)b0)[ct];
        float a0[8], a1[8];
        #pragma unroll
        for (int r = 0; r < 8; ++r) { a0[r] = bb.x; a1[r] = bb.y; }
        for (int k4 = 0; k4 < 64; k4 += 2) {
            #pragma unroll
            for (int c = 0; c < 4; ++c) wB[c] = wp[(4 * (k4 + 1) + c) * 64];
            #pragma unroll
            for (int r = 0; r < 8; ++r) {
                const float4 av = *(const float4*)&A[r0 + r][4 * k4];
                a0[r] = fmaf(av.x, wA[0].x, fmaf(av.y, wA[1].x, fmaf(av.z, wA[2].x, fmaf(av.w, wA[3].x, a0[r]))));
                a1[r] = fmaf(av.x, wA[0].y, fmaf(av.y, wA[1].y, fmaf(av.z, wA[2].y, fmaf(av.w, wA[3].y, a1[r]))));
            }
            #pragma unroll
            for (int c = 0; c < 4; ++c) wA[c] = wp[(4 * (k4 + 2) + c) * 64]; // benign OOB at last pair
            #pragma unroll
            for (int r = 0; r < 8; ++r) {
                const float4 av = *(const float4*)&A[r0 + r][4 * k4 + 4];
                a0[r] = fmaf(av.x, wB[0].x, fmaf(av.y, wB[1].x, fmaf(av.z, wB[2].x, fmaf(av.w, wB[3].x, a0[r]))));
                a1[r] = fmaf(av.x, wB[0].y, fmaf(av.y, wB[1].y, fmaf(av.z, wB[2].y, fmaf(av.w, wB[3].y, a1[r]))));
            }
        }
        #pragma unroll
        for (int r = 0; r < 8; ++r) {
            B[r0 + r][2 * ct]     = fmaxf(a0[r], 0.f);
            B[r0 + r][2 * ct + 1] = fmaxf(a1[r], 0.f);
        }
    }
    __syncthreads();
    // L1: 128->256 relu, B->A.  4 cols/thread (float4 weights), ping-pong.
    {
        const float4* wp = (const float4*)w1t + ct;
        float4 wA[4], wB[4];
        #pragma unroll
        for (int c = 0; c < 4; ++c) wA[c] = wp[c * 64];
        float4 bb = ((const float4*)b1)[ct];
        float acc[8][4];
        #pragma unroll
        for (int r = 0; r < 8; ++r) {
            acc[r][0] = bb.x; acc[r][1] = bb.y; acc[r][2] = bb.z; acc[r][3] = bb.w;
        }
        for (int k4 = 0; k4 < 32; k4 += 2) {
            #pragma unroll
            for (int c = 0; c < 4; ++c) wB[c] = wp[(4 * (k4 + 1) + c) * 64];
            #pragma unroll
            for (int r = 0; r < 8; ++r) {
                const float4 av = *(const float4*)&B[r0 + r][4 * k4];
                acc[r][0] = fmaf(av.x, wA[0].x, fmaf(av.y, wA[1].x, fmaf(av.z, wA[2].x, fmaf(av.w, wA[3].x, acc[r][0]))));
                acc[r][1] = fmaf(av.x, wA[0].y, fmaf(av.y, wA[1].y, fmaf(av.z, wA[2].y, fmaf(av.w, wA[3].y, acc[r][1]))));
                acc[r][2] = fmaf(av.x, wA[0].z, fmaf(av.y, wA[1].z, fmaf(av.z, wA[2].z, fmaf(av.w, wA[3].z, acc[r][2]))));
                acc[r][3] = fmaf(av.x, wA[0].w, fmaf(av.y, wA[1].w, fmaf(av.z, wA[2].w, fmaf(av.w, wA[3].w, acc[r][3]))));
            }
            #pragma unroll
            for (int c = 0; c < 4; ++c) wA[c] = wp[(4 * (k4 + 2) + c) * 64]; // benign OOB at last pair
            #pragma unroll
            for (int r = 0; r < 8; ++r) {
                const float4 av = *(const float4*)&B[r0 + r][4 * k4 + 4];
                acc[r][0] = fmaf(av.x, wB[0].x, fmaf(av.y, wB[1].x, fmaf(av.z, wB[2].x, fmaf(av.w, wB[3].x, acc[r][0]))));
                acc[r][1] = fmaf(av.x, wB[0].y, fmaf(av.y, wB[1].y, fmaf(av.z, wB[2].y, fmaf(av.w, wB[3].y, acc[r][1]))));
                acc[r][2] = fmaf(av.x, wB[0].z, fmaf(av.y, wB[1].z, fmaf(av.z, wB[2].z, fmaf(av.w, wB[3].z, acc[r][2]))));
                acc[r][3] = fmaf(av.x, wB[0].w, fmaf(av.y, wB[1].w, fmaf(av.z, wB[2].w, fmaf(av.w, wB[3].w, acc[r][3]))));
            }
        }
        #pragma unroll
        for (int r = 0; r < 8; ++r) {
            float4 v = make_float4(fmaxf(acc[r][0], 0.f), fmaxf(acc[r][1], 0.f),
                                   fmaxf(acc[r][2], 0.f), fmaxf(acc[r][3], 0.f));
            *(float4*)&A[r0 + r][4 * ct] = v;
        }
    }
    __syncthreads();
    // L2: 256->256 relu, A->A (register staged).  4 cols/thread, ping-pong.
    {
        const float4* wp = (const float4*)w2t + ct;
        float4 wA[4], wB[4];
        #pragma unroll
        for (int c = 0; c < 4; ++c) wA[c] = wp[c * 64];
        float4 bb = ((const float4*)b2)[ct];
        float acc[8][4];
        #pragma unroll
        for (int r = 0; r < 8; ++r) {
            acc[r][0] = bb.x; acc[r][1] = bb.y; acc[r][2] = bb.z; acc[r][3] = bb.w;
        }
        for (int k4 = 0; k4 < 64; k4 += 2) {
            #pragma unroll
            for (int c = 0; c < 4; ++c) wB[c] = wp[(4 * (k4 + 1) + c) * 64];
            #pragma unroll
            for (int r = 0; r < 8; ++r) {
                const float4 av = *(const float4*)&A[r0 + r][4 * k4];
                acc[r][0] = fmaf(av.x, wA[0].x, fmaf(av.y, wA[1].x, fmaf(av.z, wA[2].x, fmaf(av.w, wA[3].x, acc[r][0]))));
                acc[r][1] = fmaf(av.x, wA[0].y, fmaf(av.y, wA[1].y, fmaf(av.z, wA[2].y, fmaf(av.w, wA[3].y, acc[r][1]))));
                acc[r][2] = fmaf(av.x, wA[0].z, fmaf(av.y, wA[1].z, fmaf(av.z, wA[2].z, fmaf(av.w, wA[3].z, acc[r][2]))));
                acc[r][3] = fmaf(av.x, wA[0].w, fmaf(av.y, wA[1].w, fmaf(av.z, wA[2].w, fmaf(av.w, wA[3].w, acc[r][3]))));
            }
            #pragma unroll
            for (int c = 0; c < 4; ++c) wA[c] = wp[(4 * (k4 + 2) + c) * 64]; // benign OOB at last pair
            #pragma unroll
            for (int r = 0; r < 8; ++r) {
                const float4 av = *(const float4*)&A[r0 + r][4 * k4 + 4];
                acc[r][0] = fmaf(av.x, wB[0].x, fmaf(av.y, wB[1].x, fmaf(av.z, wB[2].x, fmaf(av.w, wB[3].x, acc[r][0]))));
                acc[r][1] = fmaf(av.x, wB[0].y, fmaf(av.y, wB[1].y, fmaf(av.z, wB[2].y, fmaf(av.w, wB[3].y, acc[r][1]))));
                acc[r][2] = fmaf(av.x, wB[0].z, fmaf(av.y, wB[1].z, fmaf(av.z, wB[2].z, fmaf(av.w, wB[3].z, acc[r][2]))));
                acc[r][3] = fmaf(av.x, wB[0].w, fmaf(av.y, wB[1].w, fmaf(av.z, wB[2].w, fmaf(av.w, wB[3].w, acc[r][3]))));
            }
        }
        __syncthreads();
        #pragma unroll
        for (int r = 0; r < 8; ++r) {
            float4 v = make_float4(fmaxf(acc[r][0], 0.f), fmaxf(acc[r][1], 0.f),
                                   fmaxf(acc[r][2], 0.f), fmaxf(acc[r][3], 0.f));
            *(float4*)&A[r0 + r][4 * ct] = v;
        }
    }
    __syncthreads();
    // L3: 256->16 relu, A->C16   (512 tasks)
    for (int idx = tid; idx < 512; idx += 256) {
        int r = idx >> 4, o = idx & 15;
        float acc = b3[o];
        for (int k4 = 0; k4 < 64; ++k4) {
            const float4 av = *(const float4*)&A[r][4 * k4];
            acc = fmaf(av.x, w3t[(4 * k4 + 0) * 16 + o],
                  fmaf(av.y, w3t[(4 * k4 + 1) * 16 + o],
                  fmaf(av.z, w3t[(4 * k4 + 2) * 16 + o],
                  fmaf(av.w, w3t[(4 * k4 + 3) * 16 + o], acc))));
        }
        C16[r][o] = fmaxf(acc, 0.f);
    }
    __syncthreads();
    // L4: 16->256 (no relu), combine dirs, /E ; write p and pT
    {
        int o = tid;
        int ai = o >> 4, aj = o & 15;
        float acc[32];
        #pragma unroll
        for (int r = 0; r < 32; ++r) acc[r] = b4[o];
        #pragma unroll
        for (int k4 = 0; k4 < 4; ++k4) {
            float w0v = w4t[(4 * k4 + 0) * 256 + o];
            float w1v = w4t[(4 * k4 + 1) * 256 + o];
            float w2v = w4t[(4 * k4 + 2) * 256 + o];
            float w3v = w4t[(4 * k4 + 3) * 256 + o];
            #pragma unroll
            for (int r = 0; r < 32; ++r) {
                const float4 av = *(const float4*)&C16[r][4 * k4];
                acc[r] = fmaf(av.x, w0v, fmaf(av.y, w1v, fmaf(av.z, w2v, fmaf(av.w, w3v, acc[r]))));
            }
        }
        #pragma unroll
        for (int s = 0; s < 16; ++s) {
            float v = 0.5f * (acc[2 * s] + acc[2 * s + 1]) * (1.f / NE);
            p_out[(e0 + s) * 256 + o] = v;
            pT[(e0 + s) * 256 + aj * 16 + ai] = v;   // pT[e][aj][ai]
        }
    }
}

// ---------------- CSR gather helper (sum of msg slots for node n, lane L) ---
__device__ __forceinline__ float gather_S(
    const float* __restrict__ msg, const int* __restrict__ base,
    const int* __restrict__ csr, int n, int L)
{
    int b = base[n], d = base[n + 1] - b;
    float s = 0.f;
    int k = 0;
    for (; k + 4 <= d; k += 4) {
        int s0 = csr[b + k], s1 = csr[b + k + 1];
        int s2 = csr[b + k + 2], s3 = csr[b + k + 3];
        s += msg[s0 * 16 + L] + msg[s1 * 16 + L]
           + msg[s2 * 16 + L] + msg[s3 * 16 + L];
    }
    for (; k < d; ++k) s += msg[csr[b + k] * 16 + L];
    return s;
}

// ---------------- merged MP iteration kernel (atomic-free S) -----------------
// msgOld = msg(t-1) (read-only this launch); msgNew = msg(t) (written).
// blocks 0..999:     edge phase iter t — gathers S for both endpoints in-thread.
// blocks 1000..1124: node argmax iter t-1 (gather msgOld) + u-part of q[t-1].
// blocks 1125..1187: p-part of q[t-2] via aidx[t-2] (written in launch t-1).
__global__ __launch_bounds__(256) void mp_iter_kernel(
    const float* __restrict__ u, const float* __restrict__ msgOld,
    float* __restrict__ msgNew, const float* __restrict__ pT,
    const float* __restrict__ p, const int* __restrict__ edges,
    const int* __restrict__ base, const int* __restrict__ csr,
    int* __restrict__ aidx, float* __restrict__ q, int t)
{
    const int tid = threadIdx.x;
    if (blockIdx.x < 1000) {
        // ---- edge phase, iter t ----
        const int gid = blockIdx.x * 256 + tid;
        const int e = gid >> 4;
        const int L = gid & 15;
        const int i = edges[2 * e], j = edges[2 * e + 1];
        const float Si = gather_S(msgOld, base, csr, i, L);
        const float Sj = gather_S(msgOld, base, csr, j, L);
        const float mold_ij = msgOld[(NE + e) * 16 + L];   // into i
        const float mold_ji = msgOld[e * 16 + L];          // into j
        const float bi = u[i * 16 + L] + Si - mold_ij;
        const float bj = u[j * 16 + L] + Sj - mold_ji;
        const float4* pt = (const float4*)(pT + e * 256 + L * 16);  // pT[e][L][*] = p[e][*][L]
        const float4 q0 = pt[0], q1 = pt[1], q2 = pt[2], q3 = pt[3];
        float pv[16] = {q0.x, q0.y, q0.z, q0.w, q1.x, q1.y, q1.z, q1.w,
                        q2.x, q2.y, q2.z, q2.w, q3.x, q3.y, q3.z, q3.w};
        float mj = -INFINITY, vmax = -INFINITY;
        #pragma unroll
        for (int a = 0; a < 16; ++a) {
            float v = pv[a];
            float bia = __shfl(bi, a, 16);
            mj = fmaxf(mj, v + bia);
            vmax = fmaxf(vmax, v);
        }
        float mi = vmax + bj;
        float sj = mj, si = mi;
        #pragma unroll
        for (int off = 1; off < 16; off <<= 1) {
            sj += __shfl_xor(sj, off, 16);
            si += __shfl_xor(si, off, 16);
        }
        mj -= sj * (1.f / 16.f);
        mi -= si * (1.f / 16.f);
        msgNew[e * 16 + L] = mj;
        msgNew[(NE + e) * 16 + L] = mi;
    } else if (blockIdx.x < 1125) {
        if (t == 0) return;
        // ---- node argmax, iter t-1 ----
        const int gid = (blockIdx.x - 1000) * 256 + tid;
        const int n = gid >> 4;
        const int L = gid & 15;
        const float uval = u[n * 16 + L];
        const float v = uval + gather_S(msgOld, base, csr, n, L);
        float bv = v; int bl = L;
        #pragma unroll
        for (int off = 1; off < 16; off <<= 1) {
            float ov = __shfl_xor(bv, off, 16);
            int   ol = __shfl_xor(bl, off, 16);
            if (ov > bv || (ov == bv && ol < bl)) { bv = ov; bl = ol; }
        }
        float partial = 0.f;
        if (L == 0) {
            aidx[(t - 1) * N_NODES + n] = bl;
            partial = u[n * 16 + bl];
        }
        #pragma unroll
        for (int off = 1; off < 64; off <<= 1) partial += __shfl_xor(partial, off, 64);
        if ((tid & 63) == 0) atomicAdd(&q[t - 1], partial);
    } else {
        if (t < 2) return;
        // ---- p-part of q, iter t-2 ----
        const int e = (blockIdx.x - 1125) * 256 + tid;
        float partial = 0.f;
        if (e < NE) {
            int i = edges[2 * e], j = edges[2 * e + 1];
            int ai = aidx[(t - 2) * N_NODES + i];
            int aj = aidx[(t - 2) * N_NODES + j];
            partial = p[e * 256 + ai * 16 + aj];
        }
        #pragma unroll
        for (int off = 1; off < 64; off <<= 1) partial += __shfl_xor(partial, off, 64);
        if ((tid & 63) == 0) atomicAdd(&q[t - 2], partial);
    }
}

// ---------------- tail1: node argmax iter 7 + p-part iter 6 ------------------
__global__ __launch_bounds__(256) void mp_tail1_kernel(
    const float* __restrict__ u, const float* __restrict__ msgLast,
    const float* __restrict__ p, const int* __restrict__ edges,
    const int* __restrict__ base, const int* __restrict__ csr,
    int* __restrict__ aidx, float* __restrict__ q)
{
    const int tid = threadIdx.x;
    if (blockIdx.x < 125) {
        const int gid = blockIdx.x * 256 + tid;
        const int n = gid >> 4;
        const int L = gid & 15;
        const float uval = u[n * 16 + L];
        const float v = uval + gather_S(msgLast, base, csr, n, L);
        float bv = v; int bl = L;
        #pragma unroll
        for (int off = 1; off < 16; off <<= 1) {
            float ov = __shfl_xor(bv, off, 16);
            int   ol = __shfl_xor(bl, off, 16);
            if (ov > bv || (ov == bv && ol < bl)) { bv = ov; bl = ol; }
        }
        float partial = 0.f;
        if (L == 0) {
            aidx[(NITERS - 1) * N_NODES + n] = bl;
            partial = u[n * 16 + bl];
        }
        #pragma unroll
        for (int off = 1; off < 64; off <<= 1) partial += __shfl_xor(partial, off, 64);
        if ((tid & 63) == 0) atomicAdd(&q[NITERS - 1], partial);
    } else {
        const int e = (blockIdx.x - 125) * 256 + tid;
        float partial = 0.f;
        if (e < NE) {
            int i = edges[2 * e], j = edges[2 * e + 1];
            int ai = aidx[(NITERS - 2) * N_NODES + i];
            int aj = aidx[(NITERS - 2) * N_NODES + j];
            partial = p[e * 256 + ai * 16 + aj];
        }
        #pragma unroll
        for (int off = 1; off < 64; off <<= 1) partial += __shfl_xor(partial, off, 64);
        if ((tid & 63) == 0) atomicAdd(&q[NITERS - 2], partial);
    }
}

// ---------------- tail2: p-part iter 7 ---------------------------------------
__global__ __launch_bounds__(256) void mp_tail2_kernel(
    const float* __restrict__ p, const int* __restrict__ edges,
    const int* __restrict__ aidx, float* __restrict__ q)
{
    const int tid = threadIdx.x;
    const int e = blockIdx.x * 256 + tid;
    float partial = 0.f;
    if (e < NE) {
        int i = edges[2 * e], j = edges[2 * e + 1];
        int ai = aidx[(NITERS - 1) * N_NODES + i];
        int aj = aidx[(NITERS - 1) * N_NODES + j];
        partial = p[e * 256 + ai * 16 + aj];
    }
    #pragma unroll
    for (int off = 1; off < 64; off <<= 1) partial += __shfl_xor(partial, off, 64);
    if ((tid & 63) == 0) atomicAdd(&q[NITERS - 1], partial);
}

// ---------------- final: running strict-> max over iters, one-hot a ----------
__global__ __launch_bounds__(256) void final_kernel(
    const float* __restrict__ q, const int* __restrict__ aidx,
    float* __restrict__ a_out, float* __restrict__ q_out)
{
    int id = blockIdx.x * 256 + threadIdx.x;
    float cur = 0.f; int best_t = -1;
    #pragma unroll
    for (int t = 0; t < NITERS; ++t) {
        float qv = q[t];
        if (qv > cur) { cur = qv; best_t = t; }
    }
    if (id < N_NODES * 16) {
        int n = id >> 4, c = id & 15;
        float val = 0.f;
        if (best_t >= 0 && aidx[best_t * N_NODES + n] == c) val = 1.f;
        a_out[id] = val;
        if (id == 0) q_out[0] = cur;
    }
}

extern "C" void kernel_launch(void* const* d_in, const int* in_sizes, int n_in,
                              void* d_out, int out_size, void* d_ws, size_t ws_size,
                              hipStream_t stream)
{
    (void)in_sizes; (void)n_in; (void)out_size; (void)ws_size;
    const float* x    = (const float*)d_in[0];
    const float* pa   = (const float*)d_in[1];
    const float* st   = (const float*)d_in[2];
    const int*   edges= (const int*)d_in[3];
    const float* gwih = (const float*)d_in[4];
    const float* gwhh = (const float*)d_in[5];
    const float* gbih = (const float*)d_in[6];
    const float* gbhh = (const float*)d_in[7];
    const float* uW0 = (const float*)d_in[8];  const float* ub0 = (const float*)d_in[9];
    const float* uW1 = (const float*)d_in[10]; const float* ub1 = (const float*)d_in[11];
    const float* uW2 = (const float*)d_in[12]; const float* ub2 = (const float*)d_in[13];
    const float* pW0 = (const float*)d_in[14]; const float* pb0 = (const float*)d_in[15];
    const float* pW1 = (const float*)d_in[16]; const float* pb1 = (const float*)d_in[17];
    const float* pW2 = (const float*)d_in[18]; const float* pb2 = (const float*)d_in[19];
    const float* pW3 = (const float*)d_in[20]; const float* pb3 = (const float*)d_in[21];
    const float* pW4 = (const float*)d_in[22]; const float* pb4 = (const float*)d_in[23];

    float* out   = (float*)d_out;
    float* a_out = out;                 // 32000
    float* q_out = out + 32000;         // 1
    float* u_out = out + 32001;         // 32000
    float* p_out = out + 64001;         // 4,096,000
    float* h_out = out + 4160001;       // 256,000 (state_out)

    float* ws    = (float*)d_ws;
    float* msg0  = ws + WS_MSG0;
    float* msg1  = ws + WS_MSG1;
    float* q     = ws + WS_Q;
    int*   deg   = (int*)(ws + WS_DEG);
    int*   cur   = (int*)(ws + WS_CUR);
    int*   aidx  = (int*)(ws + WS_AIDX);
    int*   base  = (int*)(ws + WS_BASE);
    int*   csr   = (int*)(ws + WS_CSR);
    int*   wfl   = (int*)(ws + WS_W);
    float* pT    = ws + WS_PT;
    int*   owner = (int*)(ws + WS_PT);  // aliases pT; dead before pmlp runs

    setup_kernel<<<1024, 256, 0, stream>>>(ws, uW0, uW1, uW2, pW0, pW1, pW2, pW3, pW4,
                                           gwih, gwhh);
    init_owner_kernel<<<(NE + 255) / 256, 256, 0, stream>>>(edges, owner);
    claim_kernel<<<(NE + 255) / 256, 256, 0, stream>>>(edges, owner);
    resolve_kernel<<<(NE + 255) / 256, 256, 0, stream>>>(edges, owner, wfl, deg);
    scan_kernel<<<1, 256, 0, stream>>>(deg, base);
    fill_kernel<<<(NE + 255) / 256, 256, 0, stream>>>(edges, wfl, base, cur, csr);
    gru_kernel<<<N_NODES / 8, 256, 0, stream>>>(x, pa, st, ws + WS_GIT, ws + WS_GHT,
                                                gbih, gbhh, h_out);
    umlp_kernel<<<N_NODES / 8, 256, 0, stream>>>(h_out, ws + WS_UW0T, ub0,
                                                 ws + WS_UW1T, ub1, ws + WS_UW2T, ub2,
                                                 u_out);
    pmlp_kernel<<<NE / 16, 256, 0, stream>>>(h_out, edges,
                                             ws + WS_PW0T, pb0, ws + WS_PW1T, pb1,
                                             ws + WS_PW2T, pb2, ws + WS_PW3T, pb3,
                                             ws + WS_PW4T, pb4, p_out, pT);
    for (int t = 0; t < NITERS; ++t) {
        const float* mo = (t & 1) ? msg1 : msg0;
        float*       mn = (t & 1) ? msg0 : msg1;
        mp_iter_kernel<<<1188, 256, 0, stream>>>(u_out, mo, mn, pT, p_out,
                                                 edges, base, csr, aidx, q, t);
    }
    // msg(7) lives in msg0 (t=7 wrote mn = msg0)
    mp_tail1_kernel<<<188, 256, 0, stream>>>(u_out, msg0, p_out, edges, base, csr,
                                             aidx, q);
    mp_tail2_kernel<<<63, 256, 0, stream>>>(p_out, edges, aidx, q);
    final_kernel<<<125, 256, 0, stream>>>(q, aidx, a_out, q_out);
}

// Round 9
// 370.047 us; speedup vs baseline: 1.3308x; 1.3308x over previous
//
#include <hip/hip_runtime.h>
#include <math.h>

#define N_NODES 2000
#define NA 16
#define NOBS 64
#define NH 128
#define NE 16000
#define NITERS 8

// ---------------- workspace layout (float offsets) ----------------
#define WS_MSG       0                       // 2E*16 = 512000
#define WS_Q         512000                  // 8
#define WS_ZERO_CNT  512008                  // msg + q zeroed in setup
#define WS_SBUF      512016                  // 9 x 32000 uS buffers (u-initialized by umlp)
#define WS_AIDX      800016                  // int[8*2000]
#define WS_W         816016                  // int[16000] wflag
#define WS_PT        832016                  // pT 4,096,000; owner map (4,000,000 ints) aliases
#define WS_GIT       (WS_PT + 4000000)       // gru wihT k-panel 80x384 = 30720 (dead after gru)
#define WS_GHT       (WS_GIT + 30720)        // gru whhT k-panel 128x384 = 49152
#define WS_WB        4928016                 // transposed weights base
#define WS_UW0T      (WS_WB + 0)             // 128x256
#define WS_UW1T      (WS_WB + 32768)         // 256x256
#define WS_UW2T      (WS_WB + 98304)         // 256x16
#define WS_PW0T      (WS_WB + 102400)        // 256x128
#define WS_PW1T      (WS_WB + 135168)        // 128x256
#define WS_PW2T      (WS_WB + 167936)        // 256x256
#define WS_PW3T      (WS_WB + 233472)        // 256x16
#define WS_PW4T      (WS_WB + 237568)        // 16x256
// end: 5,169,680 floats (~20.7 MB)
// NOTE: weight ping-pong prefetch reads up to ~2K floats past an array's
// end — always lands in the NEXT array in this layout (benign).

// ---------------- setup: zero msg/q, transpose weights ----------------------
__global__ __launch_bounds__(256) void setup_kernel(
    float* __restrict__ ws,
    const float* __restrict__ uW0, const float* __restrict__ uW1,
    const float* __restrict__ uW2, const float* __restrict__ pW0,
    const float* __restrict__ pW1, const float* __restrict__ pW2,
    const float* __restrict__ pW3, const float* __restrict__ pW4,
    const float* __restrict__ gwih, const float* __restrict__ gwhh)
{
    const int total = WS_ZERO_CNT + 321536;
    for (int idx = blockIdx.x * 256 + threadIdx.x; idx < total;
         idx += gridDim.x * 256) {
        if (idx < WS_ZERO_CNT) {
            ws[idx] = 0.f;
        } else {
            int t = idx - WS_ZERO_CNT;
            if (t < 241664) {
                const float* src; float* dst; int K, O;
                if      (t < 32768)              { src = uW0;  dst = ws + WS_UW0T; K = 128; O = 256; }
                else if (t < 98304)  { t -= 32768;  src = uW1;  dst = ws + WS_UW1T; K = 256; O = 256; }
                else if (t < 102400) { t -= 98304;  src = uW2;  dst = ws + WS_UW2T; K = 256; O = 16;  }
                else if (t < 135168) { t -= 102400; src = pW0;  dst = ws + WS_PW0T; K = 256; O = 128; }
                else if (t < 167936) { t -= 135168; src = pW1;  dst = ws + WS_PW1T; K = 128; O = 256; }
                else if (t < 233472) { t -= 167936; src = pW2;  dst = ws + WS_PW2T; K = 256; O = 256; }
                else if (t < 237568) { t -= 233472; src = pW3;  dst = ws + WS_PW3T; K = 256; O = 16;  }
                else                 { t -= 237568; src = pW4;  dst = ws + WS_PW4T; K = 16;  O = 256; }
                int k = t / O, o = t % O;
                dst[t] = src[o * K + k];
                (void)K;
            } else if (t < 272384) {
                t -= 241664;   // gru wihT k-panel: dst[k4*1536+g*4+c] = gwih[g*80+4k4+c]
                int k4 = t / 1536, r = t % 1536, g = r >> 2, c = r & 3;
                ws[WS_GIT + t] = gwih[g * 80 + 4 * k4 + c];
            } else {
                t -= 272384;
                int k4 = t / 1536, r = t % 1536, g = r >> 2, c = r & 3;
                ws[WS_GHT + t] = gwhh[g * 128 + 4 * k4 + c];
            }
        }
    }
}

// ---------------- dedup: init touched owner slots, claim, resolve -----------
__global__ __launch_bounds__(256) void init_owner_kernel(
    const int* __restrict__ edges, int* __restrict__ owner)
{
    int e = blockIdx.x * 256 + threadIdx.x;
    if (e < NE) {
        int i = edges[2 * e], j = edges[2 * e + 1];
        owner[i * N_NODES + j] = -1;
    }
}

__global__ __launch_bounds__(256) void claim_kernel(
    const int* __restrict__ edges, int* __restrict__ owner)
{
    int e = blockIdx.x * 256 + threadIdx.x;
    if (e < NE) {
        int i = edges[2 * e], j = edges[2 * e + 1];
        atomicMax(&owner[i * N_NODES + j], e);
    }
}

__global__ __launch_bounds__(256) void resolve_kernel(
    const int* __restrict__ edges, const int* __restrict__ owner,
    int* __restrict__ wflag)
{
    int e = blockIdx.x * 256 + threadIdx.x;
    if (e < NE) {
        int i = edges[2 * e], j = edges[2 * e + 1];
        wflag[e] = (owner[i * N_NODES + j] == e) ? 1 : 0;
    }
}

// ---------------- GRU encoder -------------------------------------------------
__global__ __launch_bounds__(256) void gru_kernel(
    const float* __restrict__ x, const float* __restrict__ pa,
    const float* __restrict__ st, const float* __restrict__ wihT,
    const float* __restrict__ whhT, const float* __restrict__ bih,
    const float* __restrict__ bhh, float* __restrict__ h_out)
{
    __shared__ float enc[8][80];
    __shared__ float hp[8][128];
    __shared__ float gi[8][384];
    __shared__ float gh[8][384];
    const int tid = threadIdx.x;
    const int n0 = blockIdx.x * 8;

    for (int idx = tid; idx < 8 * 80; idx += 256) {
        int r = idx / 80, c = idx % 80;
        enc[r][c] = (c < 64) ? x[(n0 + r) * 64 + c] : pa[(n0 + r) * 16 + (c - 64)];
    }
    for (int idx = tid; idx < 8 * 128; idx += 256) {
        int r = idx >> 7, c = idx & 127;
        hp[r][c] = st[(n0 + r) * 128 + c];
    }
    __syncthreads();

    for (int idx = tid; idx < 8 * 384; idx += 256) {
        int g = idx % 384, r = idx / 384;
        float s1 = bih[g];
        #pragma unroll 5
        for (int k4 = 0; k4 < 20; ++k4) {
            const float4 ev = *(const float4*)&enc[r][4 * k4];
            const float4 wv = *(const float4*)&wihT[k4 * 1536 + g * 4];
            s1 = fmaf(ev.x, wv.x, fmaf(ev.y, wv.y, fmaf(ev.z, wv.z, fmaf(ev.w, wv.w, s1))));
        }
        gi[r][g] = s1;
        float s2 = bhh[g];
        #pragma unroll 8
        for (int k4 = 0; k4 < 32; ++k4) {
            const float4 hv = *(const float4*)&hp[r][4 * k4];
            const float4 wv = *(const float4*)&whhT[k4 * 1536 + g * 4];
            s2 = fmaf(hv.x, wv.x, fmaf(hv.y, wv.y, fmaf(hv.z, wv.z, fmaf(hv.w, wv.w, s2))));
        }
        gh[r][g] = s2;
    }
    __syncthreads();

    for (int idx = tid; idx < 8 * 128; idx += 256) {
        int r = idx >> 7, c = idx & 127;
        float rr = 1.f / (1.f + expf(-(gi[r][c] + gh[r][c])));
        float zz = 1.f / (1.f + expf(-(gi[r][128 + c] + gh[r][128 + c])));
        float nn = tanhf(gi[r][256 + c] + rr * gh[r][256 + c]);
        h_out[(n0 + r) * 128 + c] = (1.f - zz) * nn + zz * hp[r][c];
    }
}

// ---------------- u MLP: 128 -> 256 -> 256 -> 16, /N ----------------
// writes u_out and initializes all 9 uS slots with u (S starts at 0;
// edge-phase atomics then accumulate on top).
__global__ __launch_bounds__(256) void umlp_kernel(
    const float* __restrict__ h, const float* __restrict__ w0t,
    const float* __restrict__ b0, const float* __restrict__ w1t,
    const float* __restrict__ b1, const float* __restrict__ w2t,
    const float* __restrict__ b2, float* __restrict__ u_out,
    float* __restrict__ Sbuf)
{
    __shared__ float A[8][128];
    __shared__ float B[8][256];
    const int tid = threadIdx.x;
    const int n0 = blockIdx.x * 8;

    for (int idx = tid; idx < 8 * 128; idx += 256) {
        int r = idx >> 7, c = idx & 127;
        A[r][c] = h[(n0 + r) * 128 + c];
    }
    __syncthreads();
    // L0: 128->256 relu, A->B
    {
        const int o = tid;
        const float* wp = w0t + o;
        float wA[4], wB[4];
        #pragma unroll
        for (int c = 0; c < 4; ++c) wA[c] = wp[c * 256];
        float acc[8];
        #pragma unroll
        for (int r = 0; r < 8; ++r) acc[r] = b0[o];
        for (int k4 = 0; k4 < 32; k4 += 2) {
            #pragma unroll
            for (int c = 0; c < 4; ++c) wB[c] = wp[(4 * (k4 + 1) + c) * 256];
            #pragma unroll
            for (int r = 0; r < 8; ++r) {
                const float4 av = *(const float4*)&A[r][4 * k4];
                acc[r] = fmaf(av.x, wA[0], fmaf(av.y, wA[1], fmaf(av.z, wA[2], fmaf(av.w, wA[3], acc[r]))));
            }
            #pragma unroll
            for (int c = 0; c < 4; ++c) wA[c] = wp[(4 * (k4 + 2) + c) * 256]; // benign OOB at last pair
            #pragma unroll
            for (int r = 0; r < 8; ++r) {
                const float4 av = *(const float4*)&A[r][4 * k4 + 4];
                acc[r] = fmaf(av.x, wB[0], fmaf(av.y, wB[1], fmaf(av.z, wB[2], fmaf(av.w, wB[3], acc[r]))));
            }
        }
        #pragma unroll
        for (int r = 0; r < 8; ++r) B[r][o] = fmaxf(acc[r], 0.f);
    }
    __syncthreads();
    // L1: 256->256 relu, B->B (register staged)
    {
        const int o = tid;
        const float* wp = w1t + o;
        float wA[4], wB[4];
        #pragma unroll
        for (int c = 0; c < 4; ++c) wA[c] = wp[c * 256];
        float acc[8];
        #pragma unroll
        for (int r = 0; r < 8; ++r) acc[r] = b1[o];
        for (int k4 = 0; k4 < 64; k4 += 2) {
            #pragma unroll
            for (int c = 0; c < 4; ++c) wB[c] = wp[(4 * (k4 + 1) + c) * 256];
            #pragma unroll
            for (int r = 0; r < 8; ++r) {
                const float4 av = *(const float4*)&B[r][4 * k4];
                acc[r] = fmaf(av.x, wA[0], fmaf(av.y, wA[1], fmaf(av.z, wA[2], fmaf(av.w, wA[3], acc[r]))));
            }
            #pragma unroll
            for (int c = 0; c < 4; ++c) wA[c] = wp[(4 * (k4 + 2) + c) * 256]; // benign OOB at last pair
            #pragma unroll
            for (int r = 0; r < 8; ++r) {
                const float4 av = *(const float4*)&B[r][4 * k4 + 4];
                acc[r] = fmaf(av.x, wB[0], fmaf(av.y, wB[1], fmaf(av.z, wB[2], fmaf(av.w, wB[3], acc[r]))));
            }
        }
        __syncthreads();
        #pragma unroll
        for (int r = 0; r < 8; ++r) B[r][o] = fmaxf(acc[r], 0.f);
    }
    __syncthreads();
    // L2: 256->16, /N, no relu (threads 0..127); fan out to u and 9 uS slots
    if (tid < 128) {
        int r = tid >> 4, o = tid & 15;
        float acc = b2[o];
        for (int k4 = 0; k4 < 64; ++k4) {
            const float4 av = *(const float4*)&B[r][4 * k4];
            acc = fmaf(av.x, w2t[(4 * k4 + 0) * 16 + o],
                  fmaf(av.y, w2t[(4 * k4 + 1) * 16 + o],
                  fmaf(av.z, w2t[(4 * k4 + 2) * 16 + o],
                  fmaf(av.w, w2t[(4 * k4 + 3) * 16 + o], acc))));
        }
        float val = acc * (1.f / N_NODES);
        int idx = (n0 + r) * 16 + o;
        u_out[idx] = val;
        #pragma unroll
        for (int t = 0; t < NITERS + 1; ++t) Sbuf[t * 32000 + idx] = val;
    }
}

// ---------------- p MLP: single-LDS-buffer version ---------------------------
// 32 rows (16 edges)/block. Rows are WAVE-PRIVATE through L0-L2 and wave
// lockstep guarantees all loads precede the post-loop stores, so each layer
// writes in place over A. LDS = 35.1 KB -> 4 blocks/CU -> 1000 blocks fit in
// ONE scheduling round (vs 2 rounds at 3/CU = the old ~50% tail).
__global__ __launch_bounds__(256, 4) void pmlp_kernel(
    const float* __restrict__ h, const int* __restrict__ edges,
    const float* __restrict__ w0t, const float* __restrict__ b0,
    const float* __restrict__ w1t, const float* __restrict__ b1,
    const float* __restrict__ w2t, const float* __restrict__ b2,
    const float* __restrict__ w3t, const float* __restrict__ b3,
    const float* __restrict__ w4t, const float* __restrict__ b4,
    float* __restrict__ p_out, float* __restrict__ pT)
{
    __shared__ float A[32][256];   // 32 KB — the only activation buffer
    __shared__ float C16[32][16];  // 2 KB
    __shared__ int fi[32], se[32];
    const int tid = threadIdx.x;
    const int e0 = blockIdx.x * 16;
    const int rg = tid >> 6;       // wave id = row group
    const int ct = tid & 63;
    const int r0 = rg * 8;

    if (tid < 16) {
        int i = edges[2 * (e0 + tid)], j = edges[2 * (e0 + tid) + 1];
        fi[2 * tid] = i;     se[2 * tid] = j;       // row 2s  = [h_i | h_j]
        fi[2 * tid + 1] = j; se[2 * tid + 1] = i;   // row 2s+1 = [h_j | h_i]
    }
    __syncthreads();
    {
        int c = tid, cl = c & 127;
        for (int r = 0; r < 32; ++r) {
            int node = (c < 128) ? fi[r] : se[r];
            A[r][c] = h[node * 128 + cl];
        }
    }
    __syncthreads();
    // L0: 256->128 relu. Reads A[r][0..255], writes A[r][0..127] (2 cols/thr).
    // Rows wave-private; all loads precede stores in the wave's instr stream.
    {
        const float2* wp = (const float2*)w0t + ct;
        float2 wA[4], wB[4];
        #pragma unroll
        for (int c = 0; c < 4; ++c) wA[c] = wp[c * 64];
        float2 bb = ((const float2*)b0)[ct];
        float a0[8], a1[8];
        #pragma unroll
        for (int r = 0; r < 8; ++r) { a0[r] = bb.x; a1[r] = bb.y; }
        for (int k4 = 0; k4 < 64; k4 += 2) {
            #pragma unroll
            for (int c = 0; c < 4; ++c) wB[c] = wp[(4 * (k4 + 1) + c) * 64];
            #pragma unroll
            for (int r = 0; r < 8; ++r) {
                const float4 av = *(const float4*)&A[r0 + r][4 * k4];
                a0[r] = fmaf(av.x, wA[0].x, fmaf(av.y, wA[1].x, fmaf(av.z, wA[2].x, fmaf(av.w, wA[3].x, a0[r]))));
                a1[r] = fmaf(av.x, wA[0].y, fmaf(av.y, wA[1].y, fmaf(av.z, wA[2].y, fmaf(av.w, wA[3].y, a1[r]))));
            }
            #pragma unroll
            for (int c = 0; c < 4; ++c) wA[c] = wp[(4 * (k4 + 2) + c) * 64]; // benign OOB at last pair
            #pragma unroll
            for (int r = 0; r < 8; ++r) {
                const float4 av = *(const float4*)&A[r0 + r][4 * k4 + 4];
                a0[r] = fmaf(av.x, wB[0].x, fmaf(av.y, wB[1].x, fmaf(av.z, wB[2].x, fmaf(av.w, wB[3].x, a0[r]))));
                a1[r] = fmaf(av.x, wB[0].y, fmaf(av.y, wB[1].y, fmaf(av.z, wB[2].y, fmaf(av.w, wB[3].y, a1[r]))));
            }
        }
        #pragma unroll
        for (int r = 0; r < 8; ++r) {
            A[r0 + r][2 * ct]     = fmaxf(a0[r], 0.f);
            A[r0 + r][2 * ct + 1] = fmaxf(a1[r], 0.f);
        }
    }
    // no __syncthreads — rows wave-private
    // L1: 128->256 relu. Reads A[r][0..127], writes A[r][0..255] (4 cols/thr).
    {
        const float4* wp = (const float4*)w1t + ct;
        float4 wA[4], wB[4];
        #pragma unroll
        for (int c = 0; c < 4; ++c) wA[c] = wp[c * 64];
        float4 bb = ((const float4*)b1)[ct];
        float acc[8][4];
        #pragma unroll
        for (int r = 0; r < 8; ++r) {
            acc[r][0] = bb.x; acc[r][1] = bb.y; acc[r][2] = bb.z; acc[r][3] = bb.w;
        }
        for (int k4 = 0; k4 < 32; k4 += 2) {
            #pragma unroll
            for (int c = 0; c < 4; ++c) wB[c] = wp[(4 * (k4 + 1) + c) * 64];
            #pragma unroll
            for (int r = 0; r < 8; ++r) {
                const float4 av = *(const float4*)&A[r0 + r][4 * k4];
                acc[r][0] = fmaf(av.x, wA[0].x, fmaf(av.y, wA[1].x, fmaf(av.z, wA[2].x, fmaf(av.w, wA[3].x, acc[r][0]))));
                acc[r][1] = fmaf(av.x, wA[0].y, fmaf(av.y, wA[1].y, fmaf(av.z, wA[2].y, fmaf(av.w, wA[3].y, acc[r][1]))));
                acc[r][2] = fmaf(av.x, wA[0].z, fmaf(av.y, wA[1].z, fmaf(av.z, wA[2].z, fmaf(av.w, wA[3].z, acc[r][2]))));
                acc[r][3] = fmaf(av.x, wA[0].w, fmaf(av.y, wA[1].w, fmaf(av.z, wA[2].w, fmaf(av.w, wA[3].w, acc[r][3]))));
            }
            #pragma unroll
            for (int c = 0; c < 4; ++c) wA[c] = wp[(4 * (k4 + 2) + c) * 64]; // benign OOB at last pair
            #pragma unroll
            for (int r = 0; r < 8; ++r) {
                const float4 av = *(const float4*)&A[r0 + r][4 * k4 + 4];
                acc[r][0] = fmaf(av.x, wB[0].x, fmaf(av.y, wB[1].x, fmaf(av.z, wB[2].x, fmaf(av.w, wB[3].x, acc[r][0]))));
                acc[r][1] = fmaf(av.x, wB[0].y, fmaf(av.y, wB[1].y, fmaf(av.z, wB[2].y, fmaf(av.w, wB[3].y, acc[r][1]))));
                acc[r][2] = fmaf(av.x, wB[0].z, fmaf(av.y, wB[1].z, fmaf(av.z, wB[2].z, fmaf(av.w, wB[3].z, acc[r][2]))));
                acc[r][3] = fmaf(av.x, wB[0].w, fmaf(av.y, wB[1].w, fmaf(av.z, wB[2].w, fmaf(av.w, wB[3].w, acc[r][3]))));
            }
        }
        #pragma unroll
        for (int r = 0; r < 8; ++r) {
            float4 v = make_float4(fmaxf(acc[r][0], 0.f), fmaxf(acc[r][1], 0.f),
                                   fmaxf(acc[r][2], 0.f), fmaxf(acc[r][3], 0.f));
            *(float4*)&A[r0 + r][4 * ct] = v;
        }
    }
    // no __syncthreads — rows wave-private
    // L2: 256->256 relu, in place (4 cols/thread).
    {
        const float4* wp = (const float4*)w2t + ct;
        float4 wA[4], wB[4];
        #pragma unroll
        for (int c = 0; c < 4; ++c) wA[c] = wp[c * 64];
        float4 bb = ((const float4*)b2)[ct];
        float acc[8][4];
        #pragma unroll
        for (int r = 0; r < 8; ++r) {
            acc[r][0] = bb.x; acc[r][1] = bb.y; acc[r][2] = bb.z; acc[r][3] = bb.w;
        }
        for (int k4 = 0; k4 < 64; k4 += 2) {
            #pragma unroll
            for (int c = 0; c < 4; ++c) wB[c] = wp[(4 * (k4 + 1) + c) * 64];
            #pragma unroll
            for (int r = 0; r < 8; ++r) {
                const float4 av = *(const float4*)&A[r0 + r][4 * k4];
                acc[r][0] = fmaf(av.x, wA[0].x, fmaf(av.y, wA[1].x, fmaf(av.z, wA[2].x, fmaf(av.w, wA[3].x, acc[r][0]))));
                acc[r][1] = fmaf(av.x, wA[0].y, fmaf(av.y, wA[1].y, fmaf(av.z, wA[2].y, fmaf(av.w, wA[3].y, acc[r][1]))));
                acc[r][2] = fmaf(av.x, wA[0].z, fmaf(av.y, wA[1].z, fmaf(av.z, wA[2].z, fmaf(av.w, wA[3].z, acc[r][2]))));
                acc[r][3] = fmaf(av.x, wA[0].w, fmaf(av.y, wA[1].w, fmaf(av.z, wA[2].w, fmaf(av.w, wA[3].w, acc[r][3]))));
            }
            #pragma unroll
            for (int c = 0; c < 4; ++c) wA[c] = wp[(4 * (k4 + 2) + c) * 64]; // benign OOB at last pair
            #pragma unroll
            for (int r = 0; r < 8; ++r) {
                const float4 av = *(const float4*)&A[r0 + r][4 * k4 + 4];
                acc[r][0] = fmaf(av.x, wB[0].x, fmaf(av.y, wB[1].x, fmaf(av.z, wB[2].x, fmaf(av.w, wB[3].x, acc[r][0]))));
                acc[r][1] = fmaf(av.x, wB[0].y, fmaf(av.y, wB[1].y, fmaf(av.z, wB[2].y, fmaf(av.w, wB[3].y, acc[r][1]))));
                acc[r][2] = fmaf(av.x, wB[0].z, fmaf(av.y, wB[1].z, fmaf(av.z, wB[2].z, fmaf(av.w, wB[3].z, acc[r][2]))));
                acc[r][3] = fmaf(av.x, wB[0].w, fmaf(av.y, wB[1].w, fmaf(av.z, wB[2].w, fmaf(av.w, wB[3].w, acc[r][3]))));
            }
        }
        #pragma unroll
        for (int r = 0; r < 8; ++r) {
            float4 v = make_float4(fmaxf(acc[r][0], 0.f), fmaxf(acc[r][1], 0.f),
                                   fmaxf(acc[r][2], 0.f), fmaxf(acc[r][3], 0.f));
            *(float4*)&A[r0 + r][4 * ct] = v;
        }
    }
    __syncthreads();   // L3 crosses waves
    // L3: 256->16 relu, A->C16   (512 tasks)
    for (int idx = tid; idx < 512; idx += 256) {
        int r = idx >> 4, o = idx & 15;
        float acc = b3[o];
        for (int k4 = 0; k4 < 64; ++k4) {
            const float4 av = *(const float4*)&A[r][4 * k4];
            acc = fmaf(av.x, w3t[(4 * k4 + 0) * 16 + o],
                  fmaf(av.y, w3t[(4 * k4 + 1) * 16 + o],
                  fmaf(av.z, w3t[(4 * k4 + 2) * 16 + o],
                  fmaf(av.w, w3t[(4 * k4 + 3) * 16 + o], acc))));
        }
        C16[r][o] = fmaxf(acc, 0.f);
    }
    __syncthreads();
    // L4: 16->256 (no relu), combine dirs, /E ; write p and pT
    {
        int o = tid;
        int ai = o >> 4, aj = o & 15;
        float acc[32];
        #pragma unroll
        for (int r = 0; r < 32; ++r) acc[r] = b4[o];
        #pragma unroll
        for (int k4 = 0; k4 < 4; ++k4) {
            float w0v = w4t[(4 * k4 + 0) * 256 + o];
            float w1v = w4t[(4 * k4 + 1) * 256 + o];
            float w2v = w4t[(4 * k4 + 2) * 256 + o];
            float w3v = w4t[(4 * k4 + 3) * 256 + o];
            #pragma unroll
            for (int r = 0; r < 32; ++r) {
                const float4 av = *(const float4*)&C16[r][4 * k4];
                acc[r] = fmaf(av.x, w0v, fmaf(av.y, w1v, fmaf(av.z, w2v, fmaf(av.w, w3v, acc[r]))));
            }
        }
        #pragma unroll
        for (int s = 0; s < 16; ++s) {
            float v = 0.5f * (acc[2 * s] + acc[2 * s + 1]) * (1.f / NE);
            p_out[(e0 + s) * 256 + o] = v;
            pT[(e0 + s) * 256 + aj * 16 + ai] = v;   // pT[e][aj][ai]
        }
    }
}

// ---------------- merged MP iteration kernel (round-7 structure) -------------
__global__ __launch_bounds__(256) void mp_iter_kernel(
    const float* __restrict__ u, float* __restrict__ Sbuf,
    float* __restrict__ msg, const float* __restrict__ pT,
    const float* __restrict__ p, const int* __restrict__ edges,
    const int* __restrict__ wflag, int* __restrict__ aidx,
    float* __restrict__ q, int t)
{
    const int tid = threadIdx.x;
    if (blockIdx.x < 1000) {
        // ---- edge phase, iter t ----
        const int gid = blockIdx.x * 256 + tid;
        const int e = gid >> 4;
        const int L = gid & 15;
        const float* uSo = Sbuf + t * 32000;
        float* uSn = Sbuf + (t + 1) * 32000;
        const int i = edges[2 * e], j = edges[2 * e + 1];
        const float mold_ij = msg[(NE + e) * 16 + L];   // into i
        const float mold_ji = msg[e * 16 + L];          // into j
        const float bi = uSo[i * 16 + L] - mold_ij;
        const float bj = uSo[j * 16 + L] - mold_ji;
        const float4* pt = (const float4*)(pT + e * 256 + L * 16);  // pT[e][L][*] = p[e][*][L]
        const float4 q0 = pt[0], q1 = pt[1], q2 = pt[2], q3 = pt[3];
        float pv[16] = {q0.x, q0.y, q0.z, q0.w, q1.x, q1.y, q1.z, q1.w,
                        q2.x, q2.y, q2.z, q2.w, q3.x, q3.y, q3.z, q3.w};
        float mj = -INFINITY, vmax = -INFINITY;
        #pragma unroll
        for (int a = 0; a < 16; ++a) {
            float v = pv[a];
            float bia = __shfl(bi, a, 16);
            mj = fmaxf(mj, v + bia);
            vmax = fmaxf(vmax, v);
        }
        float mi = vmax + bj;
        float sj = mj, si = mi;
        #pragma unroll
        for (int off = 1; off < 16; off <<= 1) {
            sj += __shfl_xor(sj, off, 16);
            si += __shfl_xor(si, off, 16);
        }
        mj -= sj * (1.f / 16.f);
        mi -= si * (1.f / 16.f);
        msg[e * 16 + L] = mj;
        msg[(NE + e) * 16 + L] = mi;
        if (wflag[e]) {  // only the representative of a duplicate pair feeds S
            atomicAdd(&uSn[j * 16 + L], mj);
            atomicAdd(&uSn[i * 16 + L], mi);
        }
    } else if (t > 0) {
        // ---- node phase, iter t-1 (uS[t] complete as of previous launch) ----
        const int r = (blockIdx.x - 1000) * 256 + tid;
        const float* Sn = Sbuf + t * 32000;    // = u + S[t]
        float partial = 0.f;
        if (r < N_NODES) {
            int n = r;
            float bv = Sn[n * 16];
            int best = 0;
            #pragma unroll
            for (int a = 1; a < 16; ++a) {
                float v = Sn[n * 16 + a];
                if (v > bv) { bv = v; best = a; }
            }
            aidx[(t - 1) * N_NODES + n] = best;
            partial = u[n * 16 + best];
        } else if (r < N_NODES + NE) {
            int ee = r - N_NODES;
            int ii = edges[2 * ee], jj = edges[2 * ee + 1];
            float bvi = Sn[ii * 16]; int ai = 0;
            #pragma unroll
            for (int a = 1; a < 16; ++a) {
                float v = Sn[ii * 16 + a];
                if (v > bvi) { bvi = v; ai = a; }
            }
            float bvj = Sn[jj * 16]; int aj = 0;
            #pragma unroll
            for (int a = 1; a < 16; ++a) {
                float v = Sn[jj * 16 + a];
                if (v > bvj) { bvj = v; aj = a; }
            }
            partial = p[ee * 256 + ai * 16 + aj];
        }
        #pragma unroll
        for (int off = 1; off < 64; off <<= 1) partial += __shfl_xor(partial, off, 64);
        if ((tid & 63) == 0) atomicAdd(&q[t - 1], partial);
    }
}

// ---------------- tail node phase for the last iteration (t = NITERS-1) -----
__global__ __launch_bounds__(256) void mp_tail_kernel(
    const float* __restrict__ u, const float* __restrict__ Sbuf,
    const float* __restrict__ p, const int* __restrict__ edges,
    int* __restrict__ aidx, float* __restrict__ q)
{
    const int tid = threadIdx.x;
    const int r = blockIdx.x * 256 + tid;
    const float* Sn = Sbuf + NITERS * 32000;   // = u + S[8]
    float partial = 0.f;
    if (r < N_NODES) {
        int n = r;
        float bv = Sn[n * 16];
        int best = 0;
        #pragma unroll
        for (int a = 1; a < 16; ++a) {
            float v = Sn[n * 16 + a];
            if (v > bv) { bv = v; best = a; }
        }
        aidx[(NITERS - 1) * N_NODES + n] = best;
        partial = u[n * 16 + best];
    } else if (r < N_NODES + NE) {
        int ee = r - N_NODES;
        int ii = edges[2 * ee], jj = edges[2 * ee + 1];
        float bvi = Sn[ii * 16]; int ai = 0;
        #pragma unroll
        for (int a = 1; a < 16; ++a) {
            float v = Sn[ii * 16 + a];
            if (v > bvi) { bvi = v; ai = a; }
        }
        float bvj = Sn[jj * 16]; int aj = 0;
        #pragma unroll
        for (int a = 1; a < 16; ++a) {
            float v = Sn[jj * 16 + a];
            if (v > bvj) { bvj = v; aj = a; }
        }
        partial = p[ee * 256 + ai * 16 + aj];
    }
    #pragma unroll
    for (int off = 1; off < 64; off <<= 1) partial += __shfl_xor(partial, off, 64);
    if ((tid & 63) == 0) atomicAdd(&q[NITERS - 1], partial);
}

// ---------------- final: running strict-> max over iters, one-hot a ---------
__global__ __launch_bounds__(256) void final_kernel(
    const float* __restrict__ q, const int* __restrict__ aidx,
    float* __restrict__ a_out, float* __restrict__ q_out)
{
    int id = blockIdx.x * 256 + threadIdx.x;
    float cur = 0.f; int best_t = -1;
    #pragma unroll
    for (int t = 0; t < NITERS; ++t) {
        float qv = q[t];
        if (qv > cur) { cur = qv; best_t = t; }
    }
    if (id < N_NODES * 16) {
        int n = id >> 4, c = id & 15;
        float val = 0.f;
        if (best_t >= 0 && aidx[best_t * N_NODES + n] == c) val = 1.f;
        a_out[id] = val;
        if (id == 0) q_out[0] = cur;
    }
}

extern "C" void kernel_launch(void* const* d_in, const int* in_sizes, int n_in,
                              void* d_out, int out_size, void* d_ws, size_t ws_size,
                              hipStream_t stream)
{
    (void)in_sizes; (void)n_in; (void)out_size; (void)ws_size;
    const float* x    = (const float*)d_in[0];
    const float* pa   = (const float*)d_in[1];
    const float* st   = (const float*)d_in[2];
    const int*   edges= (const int*)d_in[3];
    const float* gwih = (const float*)d_in[4];
    const float* gwhh = (const float*)d_in[5];
    const float* gbih = (const float*)d_in[6];
    const float* gbhh = (const float*)d_in[7];
    const float* uW0 = (const float*)d_in[8];  const float* ub0 = (const float*)d_in[9];
    const float* uW1 = (const float*)d_in[10]; const float* ub1 = (const float*)d_in[11];
    const float* uW2 = (const float*)d_in[12]; const float* ub2 = (const float*)d_in[13];
    const float* pW0 = (const float*)d_in[14]; const float* pb0 = (const float*)d_in[15];
    const float* pW1 = (const float*)d_in[16]; const float* pb1 = (const float*)d_in[17];
    const float* pW2 = (const float*)d_in[18]; const float* pb2 = (const float*)d_in[19];
    const float* pW3 = (const float*)d_in[20]; const float* pb3 = (const float*)d_in[21];
    const float* pW4 = (const float*)d_in[22]; const float* pb4 = (const float*)d_in[23];

    float* out   = (float*)d_out;
    float* a_out = out;                 // 32000
    float* q_out = out + 32000;         // 1
    float* u_out = out + 32001;         // 32000
    float* p_out = out + 64001;         // 4,096,000
    float* h_out = out + 4160001;       // 256,000 (state_out)

    float* ws   = (float*)d_ws;
    float* msg  = ws + WS_MSG;
    float* Sbuf = ws + WS_SBUF;         // uS ring: slot t = u + S[t]
    float* q    = ws + WS_Q;
    int*   aidx = (int*)(ws + WS_AIDX);
    int*   wfl  = (int*)(ws + WS_W);
    float* pT   = ws + WS_PT;
    int*   owner= (int*)(ws + WS_PT);   // aliases pT; dead before pmlp runs

    setup_kernel<<<1024, 256, 0, stream>>>(ws, uW0, uW1, uW2, pW0, pW1, pW2, pW3, pW4,
                                           gwih, gwhh);
    init_owner_kernel<<<(NE + 255) / 256, 256, 0, stream>>>(edges, owner);
    claim_kernel<<<(NE + 255) / 256, 256, 0, stream>>>(edges, owner);
    resolve_kernel<<<(NE + 255) / 256, 256, 0, stream>>>(edges, owner, wfl);
    gru_kernel<<<N_NODES / 8, 256, 0, stream>>>(x, pa, st, ws + WS_GIT, ws + WS_GHT,
                                                gbih, gbhh, h_out);
    umlp_kernel<<<N_NODES / 8, 256, 0, stream>>>(h_out, ws + WS_UW0T, ub0,
                                                 ws + WS_UW1T, ub1, ws + WS_UW2T, ub2,
                                                 u_out, Sbuf);
    pmlp_kernel<<<NE / 16, 256, 0, stream>>>(h_out, edges,
                                             ws + WS_PW0T, pb0, ws + WS_PW1T, pb1,
                                             ws + WS_PW2T, pb2, ws + WS_PW3T, pb3,
                                             ws + WS_PW4T, pb4, p_out, pT);
    for (int t = 0; t < NITERS; ++t) {
        mp_iter_kernel<<<1071, 256, 0, stream>>>(u_out, Sbuf, msg, pT, p_out,
                                                 edges, wfl, aidx, q, t);
    }
    mp_tail_kernel<<<71, 256, 0, stream>>>(u_out, Sbuf, p_out, edges, aidx, q);
    final_kernel<<<125, 256, 0, stream>>>(q, aidx, a_out, q_out);
}

// Round 10
// 340.039 us; speedup vs baseline: 1.4483x; 1.0882x over previous
//
#include <hip/hip_runtime.h>
#include <math.h>

#define N_NODES 2000
#define NA 16
#define NOBS 64
#define NH 128
#define NE 16000
#define NITERS 8

// ---------------- workspace layout (float offsets) ----------------
#define WS_MSG       0                       // 2E*16 = 512000
#define WS_Q         512000                  // 8
#define WS_ZERO_CNT  512008                  // msg + q zeroed in setup
#define WS_SBUF      512016                  // 9 x 32000 uS buffers (u-initialized by umlp)
#define WS_AIDX      800016                  // int[8*2000]
#define WS_W         816016                  // int[16000] wflag
#define WS_PT        832016                  // pT 4,096,000; owner map (4,000,000 ints) aliases
#define WS_GIT       (WS_PT + 4000000)       // gru wihT k-panel 80x384 = 30720 (dead after gru)
#define WS_GHT       (WS_GIT + 30720)        // gru whhT k-panel 128x384 = 49152 (ends < WS_WB)
#define WS_WB        4928016                 // transposed weights base (contiguous chain)
#define WS_UW0T      (WS_WB + 0)             // 128x256
#define WS_UWCAT     (WS_WB + 32768)         // 128x256  [W0a@h | W0b@h] combined
#define WS_UW1T      (WS_WB + 65536)         // 256x256
#define WS_UW2T      (WS_WB + 131072)        // 256x16
#define WS_PW1T      (WS_WB + 135168)        // 128x256
#define WS_PW2T      (WS_WB + 167936)        // 256x256
#define WS_PW3T      (WS_WB + 233472)        // 256x16
#define WS_PW4T      (WS_WB + 237568)        // 16x256
#define WS_CAB       (WS_WB + 241664)        // cab[2000][256] = 512000
// end: 5,681,680 floats (~22.7 MB)
// NOTE: weight ping-pong prefetch reads up to ~2K floats past an array's
// end — always lands in the NEXT array in the chain (benign; last array
// PW4T is only used by L4 which has no ping-pong overreach).

// ---------------- setup: zero msg/q, transpose weights ----------------------
__global__ __launch_bounds__(256) void setup_kernel(
    float* __restrict__ ws,
    const float* __restrict__ uW0, const float* __restrict__ uW1,
    const float* __restrict__ uW2, const float* __restrict__ pW0,
    const float* __restrict__ pW1, const float* __restrict__ pW2,
    const float* __restrict__ pW3, const float* __restrict__ pW4,
    const float* __restrict__ gwih, const float* __restrict__ gwhh)
{
    const int total = WS_ZERO_CNT + 321536;
    for (int idx = blockIdx.x * 256 + threadIdx.x; idx < total;
         idx += gridDim.x * 256) {
        if (idx < WS_ZERO_CNT) {
            ws[idx] = 0.f;
        } else {
            int t = idx - WS_ZERO_CNT;
            if (t < 241664) {
                float v;
                if (t < 32768) {
                    int k = t / 256, o = t % 256;           // uW0T
                    v = uW0[o * 128 + k];
                } else if (t < 65536) {
                    int q = t - 32768, k = q / 256, o = q % 256;  // UWCAT: split pW0
                    v = (o < 128) ? pW0[o * 256 + k]
                                  : pW0[(o - 128) * 256 + 128 + k];
                } else if (t < 131072) {
                    int q = t - 65536, k = q / 256, o = q % 256;  // uW1T
                    v = uW1[o * 256 + k];
                } else if (t < 135168) {
                    int q = t - 131072, k = q / 16, o = q % 16;   // uW2T
                    v = uW2[o * 256 + k];
                } else if (t < 167936) {
                    int q = t - 135168, k = q / 256, o = q % 256; // pW1T
                    v = pW1[o * 128 + k];
                } else if (t < 233472) {
                    int q = t - 167936, k = q / 256, o = q % 256; // pW2T
                    v = pW2[o * 256 + k];
                } else if (t < 237568) {
                    int q = t - 233472, k = q / 16, o = q % 16;   // pW3T
                    v = pW3[o * 256 + k];
                } else {
                    int q = t - 237568, k = q / 256, o = q % 256; // pW4T
                    v = pW4[o * 16 + k];
                }
                ws[WS_WB + t] = v;
            } else if (t < 272384) {
                int q = t - 241664;   // gru wihT k-panel
                int k4 = q / 1536, r = q % 1536, g = r >> 2, c = r & 3;
                ws[WS_GIT + q] = gwih[g * 80 + 4 * k4 + c];
            } else {
                int q = t - 272384;
                int k4 = q / 1536, r = q % 1536, g = r >> 2, c = r & 3;
                ws[WS_GHT + q] = gwhh[g * 128 + 4 * k4 + c];
            }
        }
    }
}

// ---------------- dedup: init touched owner slots, claim, resolve -----------
__global__ __launch_bounds__(256) void init_owner_kernel(
    const int* __restrict__ edges, int* __restrict__ owner)
{
    int e = blockIdx.x * 256 + threadIdx.x;
    if (e < NE) {
        int i = edges[2 * e], j = edges[2 * e + 1];
        owner[i * N_NODES + j] = -1;
    }
}

__global__ __launch_bounds__(256) void claim_kernel(
    const int* __restrict__ edges, int* __restrict__ owner)
{
    int e = blockIdx.x * 256 + threadIdx.x;
    if (e < NE) {
        int i = edges[2 * e], j = edges[2 * e + 1];
        atomicMax(&owner[i * N_NODES + j], e);
    }
}

__global__ __launch_bounds__(256) void resolve_kernel(
    const int* __restrict__ edges, const int* __restrict__ owner,
    int* __restrict__ wflag)
{
    int e = blockIdx.x * 256 + threadIdx.x;
    if (e < NE) {
        int i = edges[2 * e], j = edges[2 * e + 1];
        wflag[e] = (owner[i * N_NODES + j] == e) ? 1 : 0;
    }
}

// ---------------- GRU encoder -------------------------------------------------
__global__ __launch_bounds__(256) void gru_kernel(
    const float* __restrict__ x, const float* __restrict__ pa,
    const float* __restrict__ st, const float* __restrict__ wihT,
    const float* __restrict__ whhT, const float* __restrict__ bih,
    const float* __restrict__ bhh, float* __restrict__ h_out)
{
    __shared__ float enc[8][80];
    __shared__ float hp[8][128];
    __shared__ float gi[8][384];
    __shared__ float gh[8][384];
    const int tid = threadIdx.x;
    const int n0 = blockIdx.x * 8;

    for (int idx = tid; idx < 8 * 80; idx += 256) {
        int r = idx / 80, c = idx % 80;
        enc[r][c] = (c < 64) ? x[(n0 + r) * 64 + c] : pa[(n0 + r) * 16 + (c - 64)];
    }
    for (int idx = tid; idx < 8 * 128; idx += 256) {
        int r = idx >> 7, c = idx & 127;
        hp[r][c] = st[(n0 + r) * 128 + c];
    }
    __syncthreads();

    for (int idx = tid; idx < 8 * 384; idx += 256) {
        int g = idx % 384, r = idx / 384;
        float s1 = bih[g];
        #pragma unroll 5
        for (int k4 = 0; k4 < 20; ++k4) {
            const float4 ev = *(const float4*)&enc[r][4 * k4];
            const float4 wv = *(const float4*)&wihT[k4 * 1536 + g * 4];
            s1 = fmaf(ev.x, wv.x, fmaf(ev.y, wv.y, fmaf(ev.z, wv.z, fmaf(ev.w, wv.w, s1))));
        }
        gi[r][g] = s1;
        float s2 = bhh[g];
        #pragma unroll 8
        for (int k4 = 0; k4 < 32; ++k4) {
            const float4 hv = *(const float4*)&hp[r][4 * k4];
            const float4 wv = *(const float4*)&whhT[k4 * 1536 + g * 4];
            s2 = fmaf(hv.x, wv.x, fmaf(hv.y, wv.y, fmaf(hv.z, wv.z, fmaf(hv.w, wv.w, s2))));
        }
        gh[r][g] = s2;
    }
    __syncthreads();

    for (int idx = tid; idx < 8 * 128; idx += 256) {
        int r = idx >> 7, c = idx & 127;
        float rr = 1.f / (1.f + expf(-(gi[r][c] + gh[r][c])));
        float zz = 1.f / (1.f + expf(-(gi[r][128 + c] + gh[r][128 + c])));
        float nn = tanhf(gi[r][256 + c] + rr * gh[r][256 + c]);
        h_out[(n0 + r) * 128 + c] = (1.f - zz) * nn + zz * hp[r][c];
    }
}

// ---------------- u MLP + per-node p-L0 precompute ---------------------------
// blocks 0..249:   u MLP 128->256->256->16, /N; u_out + 9 uS slots (S starts 0)
// blocks 250..499: cab[n] = [W0a@h_n | W0b@h_n]  (p-MLP L0 decomposition;
//                  no bias/relu — added per-edge in pmlp staging)
__global__ __launch_bounds__(256) void umlp_kernel(
    const float* __restrict__ h, const float* __restrict__ w0t,
    const float* __restrict__ b0, const float* __restrict__ w1t,
    const float* __restrict__ b1, const float* __restrict__ w2t,
    const float* __restrict__ b2, const float* __restrict__ wcat,
    float* __restrict__ u_out, float* __restrict__ Sbuf,
    float* __restrict__ cab)
{
    __shared__ float A[8][128];
    __shared__ float B[8][256];
    const int tid = threadIdx.x;
    const bool is_cab = blockIdx.x >= 250;
    const int n0 = (is_cab ? blockIdx.x - 250 : blockIdx.x) * 8;

    for (int idx = tid; idx < 8 * 128; idx += 256) {
        int r = idx >> 7, c = idx & 127;
        A[r][c] = h[(n0 + r) * 128 + c];
    }
    __syncthreads();

    if (is_cab) {
        // 128->256, no bias/relu, ping-pong weights
        const int o = tid;
        const float* wp = wcat + o;
        float wA[4], wB[4];
        #pragma unroll
        for (int c = 0; c < 4; ++c) wA[c] = wp[c * 256];
        float acc[8];
        #pragma unroll
        for (int r = 0; r < 8; ++r) acc[r] = 0.f;
        for (int k4 = 0; k4 < 32; k4 += 2) {
            #pragma unroll
            for (int c = 0; c < 4; ++c) wB[c] = wp[(4 * (k4 + 1) + c) * 256];
            #pragma unroll
            for (int r = 0; r < 8; ++r) {
                const float4 av = *(const float4*)&A[r][4 * k4];
                acc[r] = fmaf(av.x, wA[0], fmaf(av.y, wA[1], fmaf(av.z, wA[2], fmaf(av.w, wA[3], acc[r]))));
            }
            #pragma unroll
            for (int c = 0; c < 4; ++c) wA[c] = wp[(4 * (k4 + 2) + c) * 256]; // benign OOB at last pair
            #pragma unroll
            for (int r = 0; r < 8; ++r) {
                const float4 av = *(const float4*)&A[r][4 * k4 + 4];
                acc[r] = fmaf(av.x, wB[0], fmaf(av.y, wB[1], fmaf(av.z, wB[2], fmaf(av.w, wB[3], acc[r]))));
            }
        }
        #pragma unroll
        for (int r = 0; r < 8; ++r) cab[(n0 + r) * 256 + o] = acc[r];
        return;
    }

    // L0: 128->256 relu, A->B
    {
        const int o = tid;
        const float* wp = w0t + o;
        float wA[4], wB[4];
        #pragma unroll
        for (int c = 0; c < 4; ++c) wA[c] = wp[c * 256];
        float acc[8];
        #pragma unroll
        for (int r = 0; r < 8; ++r) acc[r] = b0[o];
        for (int k4 = 0; k4 < 32; k4 += 2) {
            #pragma unroll
            for (int c = 0; c < 4; ++c) wB[c] = wp[(4 * (k4 + 1) + c) * 256];
            #pragma unroll
            for (int r = 0; r < 8; ++r) {
                const float4 av = *(const float4*)&A[r][4 * k4];
                acc[r] = fmaf(av.x, wA[0], fmaf(av.y, wA[1], fmaf(av.z, wA[2], fmaf(av.w, wA[3], acc[r]))));
            }
            #pragma unroll
            for (int c = 0; c < 4; ++c) wA[c] = wp[(4 * (k4 + 2) + c) * 256]; // benign OOB at last pair
            #pragma unroll
            for (int r = 0; r < 8; ++r) {
                const float4 av = *(const float4*)&A[r][4 * k4 + 4];
                acc[r] = fmaf(av.x, wB[0], fmaf(av.y, wB[1], fmaf(av.z, wB[2], fmaf(av.w, wB[3], acc[r]))));
            }
        }
        #pragma unroll
        for (int r = 0; r < 8; ++r) B[r][o] = fmaxf(acc[r], 0.f);
    }
    __syncthreads();
    // L1: 256->256 relu, B->B (register staged)
    {
        const int o = tid;
        const float* wp = w1t + o;
        float wA[4], wB[4];
        #pragma unroll
        for (int c = 0; c < 4; ++c) wA[c] = wp[c * 256];
        float acc[8];
        #pragma unroll
        for (int r = 0; r < 8; ++r) acc[r] = b1[o];
        for (int k4 = 0; k4 < 64; k4 += 2) {
            #pragma unroll
            for (int c = 0; c < 4; ++c) wB[c] = wp[(4 * (k4 + 1) + c) * 256];
            #pragma unroll
            for (int r = 0; r < 8; ++r) {
                const float4 av = *(const float4*)&B[r][4 * k4];
                acc[r] = fmaf(av.x, wA[0], fmaf(av.y, wA[1], fmaf(av.z, wA[2], fmaf(av.w, wA[3], acc[r]))));
            }
            #pragma unroll
            for (int c = 0; c < 4; ++c) wA[c] = wp[(4 * (k4 + 2) + c) * 256]; // benign OOB at last pair
            #pragma unroll
            for (int r = 0; r < 8; ++r) {
                const float4 av = *(const float4*)&B[r][4 * k4 + 4];
                acc[r] = fmaf(av.x, wB[0], fmaf(av.y, wB[1], fmaf(av.z, wB[2], fmaf(av.w, wB[3], acc[r]))));
            }
        }
        __syncthreads();
        #pragma unroll
        for (int r = 0; r < 8; ++r) B[r][o] = fmaxf(acc[r], 0.f);
    }
    __syncthreads();
    // L2: 256->16, /N, no relu (threads 0..127); fan out to u and 9 uS slots
    if (tid < 128) {
        int r = tid >> 4, o = tid & 15;
        float acc = b2[o];
        for (int k4 = 0; k4 < 64; ++k4) {
            const float4 av = *(const float4*)&B[r][4 * k4];
            acc = fmaf(av.x, w2t[(4 * k4 + 0) * 16 + o],
                  fmaf(av.y, w2t[(4 * k4 + 1) * 16 + o],
                  fmaf(av.z, w2t[(4 * k4 + 2) * 16 + o],
                  fmaf(av.w, w2t[(4 * k4 + 3) * 16 + o], acc))));
        }
        float val = acc * (1.f / N_NODES);
        int idx = (n0 + r) * 16 + o;
        u_out[idx] = val;
        #pragma unroll
        for (int t = 0; t < NITERS + 1; ++t) Sbuf[t * 32000 + idx] = val;
    }
}

// ---------------- p MLP: L0 collapsed to cab gather + add --------------------
// 32 rows (16 edges)/block, single LDS buffer (35 KB, 4 blocks/CU).
// L0 per edge-dir = relu(ca_first + cb_second + b0) — computed during staging.
__global__ __launch_bounds__(256, 4) void pmlp_kernel(
    const float* __restrict__ cab, const int* __restrict__ edges,
    const float* __restrict__ b0,
    const float* __restrict__ w1t, const float* __restrict__ b1,
    const float* __restrict__ w2t, const float* __restrict__ b2,
    const float* __restrict__ w3t, const float* __restrict__ b3,
    const float* __restrict__ w4t, const float* __restrict__ b4,
    float* __restrict__ p_out, float* __restrict__ pT)
{
    __shared__ float A[32][256];   // 32 KB — the only activation buffer
    __shared__ float C16[32][16];  // 2 KB
    __shared__ int fi[32], se[32];
    const int tid = threadIdx.x;
    const int e0 = blockIdx.x * 16;
    const int rg = tid >> 6;       // wave id = row group
    const int ct = tid & 63;
    const int r0 = rg * 8;

    if (tid < 16) {
        int i = edges[2 * (e0 + tid)], j = edges[2 * (e0 + tid) + 1];
        fi[2 * tid] = i;     se[2 * tid] = j;       // row 2s  = dir (i,j)
        fi[2 * tid + 1] = j; se[2 * tid + 1] = i;   // row 2s+1 = dir (j,i)
    }
    __syncthreads();
    // L0 (collapsed): A[r][0..127] = relu(ca[fi] + cb[se] + b0)
    {
        const int cl = tid & 127;
        const int rh = tid >> 7;   // 0 or 1: rows 0-15 / 16-31
        const float bb = b0[cl];
        #pragma unroll 4
        for (int r = rh * 16; r < rh * 16 + 16; ++r) {
            float v = cab[fi[r] * 256 + cl] + cab[se[r] * 256 + 128 + cl] + bb;
            A[r][cl] = fmaxf(v, 0.f);
        }
    }
    __syncthreads();
    // L1: 128->256 relu. Reads A[r][0..127], writes A[r][0..255] (4 cols/thr).
    // Rows wave-private from here; loads precede stores in wave program order.
    {
        const float4* wp = (const float4*)w1t + ct;
        float4 wA[4], wB[4];
        #pragma unroll
        for (int c = 0; c < 4; ++c) wA[c] = wp[c * 64];
        float4 bb = ((const float4*)b1)[ct];
        float acc[8][4];
        #pragma unroll
        for (int r = 0; r < 8; ++r) {
            acc[r][0] = bb.x; acc[r][1] = bb.y; acc[r][2] = bb.z; acc[r][3] = bb.w;
        }
        for (int k4 = 0; k4 < 32; k4 += 2) {
            #pragma unroll
            for (int c = 0; c < 4; ++c) wB[c] = wp[(4 * (k4 + 1) + c) * 64];
            #pragma unroll
            for (int r = 0; r < 8; ++r) {
                const float4 av = *(const float4*)&A[r0 + r][4 * k4];
                acc[r][0] = fmaf(av.x, wA[0].x, fmaf(av.y, wA[1].x, fmaf(av.z, wA[2].x, fmaf(av.w, wA[3].x, acc[r][0]))));
                acc[r][1] = fmaf(av.x, wA[0].y, fmaf(av.y, wA[1].y, fmaf(av.z, wA[2].y, fmaf(av.w, wA[3].y, acc[r][1]))));
                acc[r][2] = fmaf(av.x, wA[0].z, fmaf(av.y, wA[1].z, fmaf(av.z, wA[2].z, fmaf(av.w, wA[3].z, acc[r][2]))));
                acc[r][3] = fmaf(av.x, wA[0].w, fmaf(av.y, wA[1].w, fmaf(av.z, wA[2].w, fmaf(av.w, wA[3].w, acc[r][3]))));
            }
            #pragma unroll
            for (int c = 0; c < 4; ++c) wA[c] = wp[(4 * (k4 + 2) + c) * 64]; // benign OOB at last pair
            #pragma unroll
            for (int r = 0; r < 8; ++r) {
                const float4 av = *(const float4*)&A[r0 + r][4 * k4 + 4];
                acc[r][0] = fmaf(av.x, wB[0].x, fmaf(av.y, wB[1].x, fmaf(av.z, wB[2].x, fmaf(av.w, wB[3].x, acc[r][0]))));
                acc[r][1] = fmaf(av.x, wB[0].y, fmaf(av.y, wB[1].y, fmaf(av.z, wB[2].y, fmaf(av.w, wB[3].y, acc[r][1]))));
                acc[r][2] = fmaf(av.x, wB[0].z, fmaf(av.y, wB[1].z, fmaf(av.z, wB[2].z, fmaf(av.w, wB[3].z, acc[r][2]))));
                acc[r][3] = fmaf(av.x, wB[0].w, fmaf(av.y, wB[1].w, fmaf(av.z, wB[2].w, fmaf(av.w, wB[3].w, acc[r][3]))));
            }
        }
        #pragma unroll
        for (int r = 0; r < 8; ++r) {
            float4 v = make_float4(fmaxf(acc[r][0], 0.f), fmaxf(acc[r][1], 0.f),
                                   fmaxf(acc[r][2], 0.f), fmaxf(acc[r][3], 0.f));
            *(float4*)&A[r0 + r][4 * ct] = v;
        }
    }
    // no __syncthreads — rows wave-private
    // L2: 256->256 relu, in place (4 cols/thread).
    {
        const float4* wp = (const float4*)w2t + ct;
        float4 wA[4], wB[4];
        #pragma unroll
        for (int c = 0; c < 4; ++c) wA[c] = wp[c * 64];
        float4 bb = ((const float4*)b2)[ct];
        float acc[8][4];
        #pragma unroll
        for (int r = 0; r < 8; ++r) {
            acc[r][0] = bb.x; acc[r][1] = bb.y; acc[r][2] = bb.z; acc[r][3] = bb.w;
        }
        for (int k4 = 0; k4 < 64; k4 += 2) {
            #pragma unroll
            for (int c = 0; c < 4; ++c) wB[c] = wp[(4 * (k4 + 1) + c) * 64];
            #pragma unroll
            for (int r = 0; r < 8; ++r) {
                const float4 av = *(const float4*)&A[r0 + r][4 * k4];
                acc[r][0] = fmaf(av.x, wA[0].x, fmaf(av.y, wA[1].x, fmaf(av.z, wA[2].x, fmaf(av.w, wA[3].x, acc[r][0]))));
                acc[r][1] = fmaf(av.x, wA[0].y, fmaf(av.y, wA[1].y, fmaf(av.z, wA[2].y, fmaf(av.w, wA[3].y, acc[r][1]))));
                acc[r][2] = fmaf(av.x, wA[0].z, fmaf(av.y, wA[1].z, fmaf(av.z, wA[2].z, fmaf(av.w, wA[3].z, acc[r][2]))));
                acc[r][3] = fmaf(av.x, wA[0].w, fmaf(av.y, wA[1].w, fmaf(av.z, wA[2].w, fmaf(av.w, wA[3].w, acc[r][3]))));
            }
            #pragma unroll
            for (int c = 0; c < 4; ++c) wA[c] = wp[(4 * (k4 + 2) + c) * 64]; // benign OOB at last pair
            #pragma unroll
            for (int r = 0; r < 8; ++r) {
                const float4 av = *(const float4*)&A[r0 + r][4 * k4 + 4];
                acc[r][0] = fmaf(av.x, wB[0].x, fmaf(av.y, wB[1].x, fmaf(av.z, wB[2].x, fmaf(av.w, wB[3].x, acc[r][0]))));
                acc[r][1] = fmaf(av.x, wB[0].y, fmaf(av.y, wB[1].y, fmaf(av.z, wB[2].y, fmaf(av.w, wB[3].y, acc[r][1]))));
                acc[r][2] = fmaf(av.x, wB[0].z, fmaf(av.y, wB[1].z, fmaf(av.z, wB[2].z, fmaf(av.w, wB[3].z, acc[r][2]))));
                acc[r][3] = fmaf(av.x, wB[0].w, fmaf(av.y, wB[1].w, fmaf(av.z, wB[2].w, fmaf(av.w, wB[3].w, acc[r][3]))));
            }
        }
        #pragma unroll
        for (int r = 0; r < 8; ++r) {
            float4 v = make_float4(fmaxf(acc[r][0], 0.f), fmaxf(acc[r][1], 0.f),
                                   fmaxf(acc[r][2], 0.f), fmaxf(acc[r][3], 0.f));
            *(float4*)&A[r0 + r][4 * ct] = v;
        }
    }
    __syncthreads();   // L3 crosses waves
    // L3: 256->16 relu, A->C16   (512 tasks)
    for (int idx = tid; idx < 512; idx += 256) {
        int r = idx >> 4, o = idx & 15;
        float acc = b3[o];
        for (int k4 = 0; k4 < 64; ++k4) {
            const float4 av = *(const float4*)&A[r][4 * k4];
            acc = fmaf(av.x, w3t[(4 * k4 + 0) * 16 + o],
                  fmaf(av.y, w3t[(4 * k4 + 1) * 16 + o],
                  fmaf(av.z, w3t[(4 * k4 + 2) * 16 + o],
                  fmaf(av.w, w3t[(4 * k4 + 3) * 16 + o], acc))));
        }
        C16[r][o] = fmaxf(acc, 0.f);
    }
    __syncthreads();
    // L4: 16->256 (no relu), combine dirs, /E ; write p and pT
    {
        int o = tid;
        int ai = o >> 4, aj = o & 15;
        float acc[32];
        #pragma unroll
        for (int r = 0; r < 32; ++r) acc[r] = b4[o];
        #pragma unroll
        for (int k4 = 0; k4 < 4; ++k4) {
            float w0v = w4t[(4 * k4 + 0) * 256 + o];
            float w1v = w4t[(4 * k4 + 1) * 256 + o];
            float w2v = w4t[(4 * k4 + 2) * 256 + o];
            float w3v = w4t[(4 * k4 + 3) * 256 + o];
            #pragma unroll
            for (int r = 0; r < 32; ++r) {
                const float4 av = *(const float4*)&C16[r][4 * k4];
                acc[r] = fmaf(av.x, w0v, fmaf(av.y, w1v, fmaf(av.z, w2v, fmaf(av.w, w3v, acc[r]))));
            }
        }
        #pragma unroll
        for (int s = 0; s < 16; ++s) {
            float v = 0.5f * (acc[2 * s] + acc[2 * s + 1]) * (1.f / NE);
            p_out[(e0 + s) * 256 + o] = v;
            pT[(e0 + s) * 256 + aj * 16 + ai] = v;   // pT[e][aj][ai]
        }
    }
}

// ---------------- merged MP iteration kernel (round-7 structure) -------------
__global__ __launch_bounds__(256) void mp_iter_kernel(
    const float* __restrict__ u, float* __restrict__ Sbuf,
    float* __restrict__ msg, const float* __restrict__ pT,
    const float* __restrict__ p, const int* __restrict__ edges,
    const int* __restrict__ wflag, int* __restrict__ aidx,
    float* __restrict__ q, int t)
{
    const int tid = threadIdx.x;
    if (blockIdx.x < 1000) {
        // ---- edge phase, iter t ----
        const int gid = blockIdx.x * 256 + tid;
        const int e = gid >> 4;
        const int L = gid & 15;
        const float* uSo = Sbuf + t * 32000;
        float* uSn = Sbuf + (t + 1) * 32000;
        const int i = edges[2 * e], j = edges[2 * e + 1];
        const float mold_ij = msg[(NE + e) * 16 + L];   // into i
        const float mold_ji = msg[e * 16 + L];          // into j
        const float bi = uSo[i * 16 + L] - mold_ij;
        const float bj = uSo[j * 16 + L] - mold_ji;
        const float4* pt = (const float4*)(pT + e * 256 + L * 16);  // pT[e][L][*] = p[e][*][L]
        const float4 q0 = pt[0], q1 = pt[1], q2 = pt[2], q3 = pt[3];
        float pv[16] = {q0.x, q0.y, q0.z, q0.w, q1.x, q1.y, q1.z, q1.w,
                        q2.x, q2.y, q2.z, q2.w, q3.x, q3.y, q3.z, q3.w};
        float mj = -INFINITY, vmax = -INFINITY;
        #pragma unroll
        for (int a = 0; a < 16; ++a) {
            float v = pv[a];
            float bia = __shfl(bi, a, 16);
            mj = fmaxf(mj, v + bia);
            vmax = fmaxf(vmax, v);
        }
        float mi = vmax + bj;
        float sj = mj, si = mi;
        #pragma unroll
        for (int off = 1; off < 16; off <<= 1) {
            sj += __shfl_xor(sj, off, 16);
            si += __shfl_xor(si, off, 16);
        }
        mj -= sj * (1.f / 16.f);
        mi -= si * (1.f / 16.f);
        msg[e * 16 + L] = mj;
        msg[(NE + e) * 16 + L] = mi;
        if (wflag[e]) {  // only the representative of a duplicate pair feeds S
            atomicAdd(&uSn[j * 16 + L], mj);
            atomicAdd(&uSn[i * 16 + L], mi);
        }
    } else if (t > 0) {
        // ---- node phase, iter t-1 (uS[t] complete as of previous launch) ----
        const int r = (blockIdx.x - 1000) * 256 + tid;
        const float* Sn = Sbuf + t * 32000;    // = u + S[t]
        float partial = 0.f;
        if (r < N_NODES) {
            int n = r;
            float bv = Sn[n * 16];
            int best = 0;
            #pragma unroll
            for (int a = 1; a < 16; ++a) {
                float v = Sn[n * 16 + a];
                if (v > bv) { bv = v; best = a; }
            }
            aidx[(t - 1) * N_NODES + n] = best;
            partial = u[n * 16 + best];
        } else if (r < N_NODES + NE) {
            int ee = r - N_NODES;
            int ii = edges[2 * ee], jj = edges[2 * ee + 1];
            float bvi = Sn[ii * 16]; int ai = 0;
            #pragma unroll
            for (int a = 1; a < 16; ++a) {
                float v = Sn[ii * 16 + a];
                if (v > bvi) { bvi = v; ai = a; }
            }
            float bvj = Sn[jj * 16]; int aj = 0;
            #pragma unroll
            for (int a = 1; a < 16; ++a) {
                float v = Sn[jj * 16 + a];
                if (v > bvj) { bvj = v; aj = a; }
            }
            partial = p[ee * 256 + ai * 16 + aj];
        }
        #pragma unroll
        for (int off = 1; off < 64; off <<= 1) partial += __shfl_xor(partial, off, 64);
        if ((tid & 63) == 0) atomicAdd(&q[t - 1], partial);
    }
}

// ---------------- tail node phase for the last iteration (t = NITERS-1) -----
__global__ __launch_bounds__(256) void mp_tail_kernel(
    const float* __restrict__ u, const float* __restrict__ Sbuf,
    const float* __restrict__ p, const int* __restrict__ edges,
    int* __restrict__ aidx, float* __restrict__ q)
{
    const int tid = threadIdx.x;
    const int r = blockIdx.x * 256 + tid;
    const float* Sn = Sbuf + NITERS * 32000;   // = u + S[8]
    float partial = 0.f;
    if (r < N_NODES) {
        int n = r;
        float bv = Sn[n * 16];
        int best = 0;
        #pragma unroll
        for (int a = 1; a < 16; ++a) {
            float v = Sn[n * 16 + a];
            if (v > bv) { bv = v; best = a; }
        }
        aidx[(NITERS - 1) * N_NODES + n] = best;
        partial = u[n * 16 + best];
    } else if (r < N_NODES + NE) {
        int ee = r - N_NODES;
        int ii = edges[2 * ee], jj = edges[2 * ee + 1];
        float bvi = Sn[ii * 16]; int ai = 0;
        #pragma unroll
        for (int a = 1; a < 16; ++a) {
            float v = Sn[ii * 16 + a];
            if (v > bvi) { bvi = v; ai = a; }
        }
        float bvj = Sn[jj * 16]; int aj = 0;
        #pragma unroll
        for (int a = 1; a < 16; ++a) {
            float v = Sn[jj * 16 + a];
            if (v > bvj) { bvj = v; aj = a; }
        }
        partial = p[ee * 256 + ai * 16 + aj];
    }
    #pragma unroll
    for (int off = 1; off < 64; off <<= 1) partial += __shfl_xor(partial, off, 64);
    if ((tid & 63) == 0) atomicAdd(&q[NITERS - 1], partial);
}

// ---------------- final: running strict-> max over iters, one-hot a ---------
__global__ __launch_bounds__(256) void final_kernel(
    const float* __restrict__ q, const int* __restrict__ aidx,
    float* __restrict__ a_out, float* __restrict__ q_out)
{
    int id = blockIdx.x * 256 + threadIdx.x;
    float cur = 0.f; int best_t = -1;
    #pragma unroll
    for (int t = 0; t < NITERS; ++t) {
        float qv = q[t];
        if (qv > cur) { cur = qv; best_t = t; }
    }
    if (id < N_NODES * 16) {
        int n = id >> 4, c = id & 15;
        float val = 0.f;
        if (best_t >= 0 && aidx[best_t * N_NODES + n] == c) val = 1.f;
        a_out[id] = val;
        if (id == 0) q_out[0] = cur;
    }
}

extern "C" void kernel_launch(void* const* d_in, const int* in_sizes, int n_in,
                              void* d_out, int out_size, void* d_ws, size_t ws_size,
                              hipStream_t stream)
{
    (void)in_sizes; (void)n_in; (void)out_size; (void)ws_size;
    const float* x    = (const float*)d_in[0];
    const float* pa   = (const float*)d_in[1];
    const float* st   = (const float*)d_in[2];
    const int*   edges= (const int*)d_in[3];
    const float* gwih = (const float*)d_in[4];
    const float* gwhh = (const float*)d_in[5];
    const float* gbih = (const float*)d_in[6];
    const float* gbhh = (const float*)d_in[7];
    const float* uW0 = (const float*)d_in[8];  const float* ub0 = (const float*)d_in[9];
    const float* uW1 = (const float*)d_in[10]; const float* ub1 = (const float*)d_in[11];
    const float* uW2 = (const float*)d_in[12]; const float* ub2 = (const float*)d_in[13];
    const float* pW0 = (const float*)d_in[14]; const float* pb0 = (const float*)d_in[15];
    const float* pW1 = (const float*)d_in[16]; const float* pb1 = (const float*)d_in[17];
    const float* pW2 = (const float*)d_in[18]; const float* pb2 = (const float*)d_in[19];
    const float* pW3 = (const float*)d_in[20]; const float* pb3 = (const float*)d_in[21];
    const float* pW4 = (const float*)d_in[22]; const float* pb4 = (const float*)d_in[23];

    float* out   = (float*)d_out;
    float* a_out = out;                 // 32000
    float* q_out = out + 32000;         // 1
    float* u_out = out + 32001;         // 32000
    float* p_out = out + 64001;         // 4,096,000
    float* h_out = out + 4160001;       // 256,000 (state_out)

    float* ws   = (float*)d_ws;
    float* msg  = ws + WS_MSG;
    float* Sbuf = ws + WS_SBUF;         // uS ring: slot t = u + S[t]
    float* q    = ws + WS_Q;
    int*   aidx = (int*)(ws + WS_AIDX);
    int*   wfl  = (int*)(ws + WS_W);
    float* pT   = ws + WS_PT;
    float* cab  = ws + WS_CAB;
    int*   owner= (int*)(ws + WS_PT);   // aliases pT; dead before pmlp runs

    setup_kernel<<<1024, 256, 0, stream>>>(ws, uW0, uW1, uW2, pW0, pW1, pW2, pW3, pW4,
                                           gwih, gwhh);
    init_owner_kernel<<<(NE + 255) / 256, 256, 0, stream>>>(edges, owner);
    claim_kernel<<<(NE + 255) / 256, 256, 0, stream>>>(edges, owner);
    resolve_kernel<<<(NE + 255) / 256, 256, 0, stream>>>(edges, owner, wfl);
    gru_kernel<<<N_NODES / 8, 256, 0, stream>>>(x, pa, st, ws + WS_GIT, ws + WS_GHT,
                                                gbih, gbhh, h_out);
    umlp_kernel<<<500, 256, 0, stream>>>(h_out, ws + WS_UW0T, ub0,
                                         ws + WS_UW1T, ub1, ws + WS_UW2T, ub2,
                                         ws + WS_UWCAT, u_out, Sbuf, cab);
    pmlp_kernel<<<NE / 16, 256, 0, stream>>>(cab, edges, pb0,
                                             ws + WS_PW1T, pb1,
                                             ws + WS_PW2T, pb2, ws + WS_PW3T, pb3,
                                             ws + WS_PW4T, pb4, p_out, pT);
    for (int t = 0; t < NITERS; ++t) {
        mp_iter_kernel<<<1071, 256, 0, stream>>>(u_out, Sbuf, msg, pT, p_out,
                                                 edges, wfl, aidx, q, t);
    }
    mp_tail_kernel<<<71, 256, 0, stream>>>(u_out, Sbuf, p_out, edges, aidx, q);
    final_kernel<<<125, 256, 0, stream>>>(q, aidx, a_out, q_out);
}